// Round 3
// baseline (6668.626 us; speedup 1.0000x reference)
//
#include <hip/hip_runtime.h>
#include <cstddef>

// ---------------------------------------------------------------------------
// SpatialAudioRenderer on MI355X — fp32 v3 (fully fp32; bf16 LDS h2 removed).
//
// R1 post-mortem: absmax 2.0020e-2 vs 2.0e-2 threshold — the bf16 h2 round
// trip in conv2_final was the only sub-fp32 link. v3 shrinks conv2_final's
// tile to 64 output cols so the h2 tile fits LDS in fp32 (128ch x 80col).
//
// Pipeline (11 launches, deterministic, no atomics, ws use ~8.9 MB):
//  1. conv1_stats (x)           -> partialsA
//  2. reduce_coef               -> coef1
//  3. conv2_big<0> (spatial)    -> partialsB(d_out) + c2head[t=0..3]
//  4. reduce_coef               -> coef2
//  5. finalize_spatial          -> wgbuf (HRTF gather * dist)
//  6. mix_kernel                -> summed (B,2,T)
//  7. conv1_stats (summed)      -> partialsA
//  8. reduce_coef               -> coefR1
//  9. conv2_big<1> (renderer)   -> partialsB(d_out)   [stats only]
// 10. reduce_coef               -> coefR2
// 11. conv2_final               -> recompute conv2 (64-col tile), bn2+lrelu,
//                                  conv3 + tanh -> d_out   [all fp32]
// ---------------------------------------------------------------------------

#define TLEN 131072
#define NB 8
#define NICH 2
#define NHID 64
#define NH2 128
#define EPSV 1e-5f
#define CNTF 1048576.0f  // NB * TLEN

__device__ __forceinline__ float lrelu(float v) { return v >= 0.f ? v : 0.2f * v; }

// ---------------------------------------------------------------------------
// Kernel 1/7: conv1 (Cin=2, Cout=64, K=7, SAME) -> per-block channel sum/sumsq.
// ---------------------------------------------------------------------------
#define TCH1 1024
__global__ __launch_bounds__(256) void conv1_stats(
    const float* __restrict__ x, const float* __restrict__ W,
    const float* __restrict__ bias, float* __restrict__ partials)
{
  const int b = blockIdx.x >> 7;              // TLEN/TCH1 = 128 chunks
  const int t0 = (blockIdx.x & 127) * TCH1;
  __shared__ float xs[2 * 1032];
  __shared__ float red[512];

  for (int i = 0; i < 2; ++i)
    for (int j = threadIdx.x; j < TCH1 + 6; j += 256) {
      int tg = t0 - 3 + j;
      xs[i * 1032 + j] = (tg >= 0 && tg < TLEN) ? x[(b * NICH + i) * TLEN + tg] : 0.f;
    }
  __syncthreads();

  const int o = threadIdx.x & 63;
  const int sub = threadIdx.x >> 6;
  float w[14];
  #pragma unroll
  for (int j = 0; j < 14; ++j) w[j] = W[o * 14 + j];
  const float bo = bias[o];

  float s = 0.f, ss = 0.f;
  const int tbeg = sub * (TCH1 / 4), tend = tbeg + TCH1 / 4;
  for (int tt = tbeg; tt < tend; tt += 4) {
    float a4[2][10];
    #pragma unroll
    for (int i = 0; i < 2; ++i) {
      const float* xp = &xs[i * 1032 + tt];
      float4 v0 = *reinterpret_cast<const float4*>(xp);
      float4 v1 = *reinterpret_cast<const float4*>(xp + 4);
      float2 v2 = *reinterpret_cast<const float2*>(xp + 8);
      a4[i][0] = v0.x; a4[i][1] = v0.y; a4[i][2] = v0.z; a4[i][3] = v0.w;
      a4[i][4] = v1.x; a4[i][5] = v1.y; a4[i][6] = v1.z; a4[i][7] = v1.w;
      a4[i][8] = v2.x; a4[i][9] = v2.y;
    }
    #pragma unroll
    for (int tq = 0; tq < 4; ++tq) {
      float acc = bo;
      #pragma unroll
      for (int i = 0; i < 2; ++i)
        #pragma unroll
        for (int k = 0; k < 7; ++k)
          acc += a4[i][tq + k] * w[i * 7 + k];
      s += acc; ss += acc * acc;
    }
  }
  red[o * 4 + sub] = s;
  red[(64 + o) * 4 + sub] = ss;
  __syncthreads();
  if (threadIdx.x < 128) {
    const float* r = &red[threadIdx.x * 4];
    partials[blockIdx.x * 128 + threadIdx.x] = r[0] + r[1] + r[2] + r[3];
  }
}

// ---------------------------------------------------------------------------
// Kernel 2: reduce partials -> bn affine coefs a = g*rsqrt(var+eps),
// d = beta - mean*a.
// ---------------------------------------------------------------------------
__global__ __launch_bounds__(256) void reduce_coef(
    const float* __restrict__ partials, int nblocks, int C,
    const float* __restrict__ g, const float* __restrict__ be,
    float* __restrict__ coef)
{
  const int c = blockIdx.x;
  float s = 0.f, ss = 0.f;
  for (int j = threadIdx.x; j < nblocks; j += 256) {
    s  += partials[j * 2 * C + c];
    ss += partials[j * 2 * C + C + c];
  }
  #pragma unroll
  for (int off = 32; off >= 1; off >>= 1) {
    s  += __shfl_down(s, off, 64);
    ss += __shfl_down(ss, off, 64);
  }
  __shared__ float rs[4], rss[4];
  const int lane = threadIdx.x & 63, wv = threadIdx.x >> 6;
  if (lane == 0) { rs[wv] = s; rss[wv] = ss; }
  __syncthreads();
  if (threadIdx.x == 0) {
    float st  = rs[0] + rs[1] + rs[2] + rs[3];
    float sst = rss[0] + rss[1] + rss[2] + rss[3];
    float mean = st / CNTF;
    float var  = sst / CNTF - mean * mean;
    float a = g[c] * rsqrtf(var + EPSV);
    coef[c] = a;
    coef[C + c] = be[c] - mean * a;
  }
}

// ---------------------------------------------------------------------------
// Kernel 3/9: fused h1 = lrelu(bn1(conv1(x))) + conv2 (64->128, K=7), stats.
// MODE 0 (spatial): also emit c2[t=0..3] head. MODE 1: stats only.
// ---------------------------------------------------------------------------
template<int MODE>
__global__ __launch_bounds__(256) void conv2_big(
    const float* __restrict__ xin,
    const float* __restrict__ W1c, const float* __restrict__ b1c,
    const float* __restrict__ coef1,
    const float* __restrict__ W2c, const float* __restrict__ b2c,
    float* __restrict__ partials,
    float* __restrict__ c2head)
{
  const int b  = blockIdx.x >> 10;            // TLEN/128 = 1024 chunks
  const int t0 = (blockIdx.x & 1023) * 128;

  __shared__ float h1s[NHID * 136];           // cols t0-3 .. t0+132 (134 used)
  __shared__ float w2s[4 * 7 * 128];          // [i2*7+k][o]
  __shared__ float xs[2 * 144];               // t0-6 .. t0+137
  __shared__ float w1s[NHID * 14];

  for (int e = threadIdx.x; e < 2 * 144; e += 256) {
    int i = e / 144, j = e % 144;
    int tg = t0 - 6 + j;
    xs[e] = (tg >= 0 && tg < TLEN) ? xin[(b * NICH + i) * TLEN + tg] : 0.f;
  }
  for (int e = threadIdx.x; e < NHID * 14; e += 256) w1s[e] = W1c[e];
  __syncthreads();

  for (int e = threadIdx.x; e < NHID * 34; e += 256) {
    int i = e / 34, q = (e % 34) * 4;
    const float a1 = coef1[i], d1 = coef1[NHID + i];
    const float bo = b1c[i];
    float a4[2][10];
    #pragma unroll
    for (int i2 = 0; i2 < 2; ++i2) {
      const float* xp = &xs[i2 * 144 + q];
      float4 v0 = *reinterpret_cast<const float4*>(xp);
      float4 v1 = *reinterpret_cast<const float4*>(xp + 4);
      float2 v2 = *reinterpret_cast<const float2*>(xp + 8);
      a4[i2][0] = v0.x; a4[i2][1] = v0.y; a4[i2][2] = v0.z; a4[i2][3] = v0.w;
      a4[i2][4] = v1.x; a4[i2][5] = v1.y; a4[i2][6] = v1.z; a4[i2][7] = v1.w;
      a4[i2][8] = v2.x; a4[i2][9] = v2.y;
    }
    float out4[4];
    #pragma unroll
    for (int tq = 0; tq < 4; ++tq) {
      int tg = t0 - 3 + q + tq;
      float acc = bo;
      #pragma unroll
      for (int i2 = 0; i2 < 2; ++i2)
        #pragma unroll
        for (int k = 0; k < 7; ++k)
          acc += a4[i2][tq + k] * w1s[i * 14 + i2 * 7 + k];
      float v = lrelu(a1 * acc + d1);
      out4[tq] = (tg >= 0 && tg < TLEN) ? v : 0.f;  // bn-of-pad trap
    }
    *reinterpret_cast<float4*>(&h1s[i * 136 + q]) =
        make_float4(out4[0], out4[1], out4[2], out4[3]);
  }
  __syncthreads();

  const int o0  = (threadIdx.x & 15) * 8;
  const int tg  = threadIdx.x >> 4;
  const int tt0 = tg * 8;

  float acc[8][8];
  #pragma unroll
  for (int a = 0; a < 8; ++a)
    #pragma unroll
    for (int q = 0; q < 8; ++q) acc[a][q] = 0.f;

  for (int ic = 0; ic < NHID; ic += 4) {
    __syncthreads();
    for (int e = threadIdx.x; e < 4 * 7 * 128; e += 256) {
      int o = e & 127, kk = e >> 7;
      w2s[e] = W2c[o * (NHID * 7) + ic * 7 + kk];
    }
    __syncthreads();
    #pragma unroll
    for (int i2 = 0; i2 < 4; ++i2) {
      float hv[14];
      #pragma unroll
      for (int j = 0; j < 14; ++j) hv[j] = h1s[(ic + i2) * 136 + tt0 + j];
      #pragma unroll
      for (int k = 0; k < 7; ++k) {
        float w8[8];
        #pragma unroll
        for (int oo = 0; oo < 8; ++oo) w8[oo] = w2s[(i2 * 7 + k) * 128 + o0 + oo];
        #pragma unroll
        for (int oo = 0; oo < 8; ++oo)
          #pragma unroll
          for (int ttt = 0; ttt < 8; ++ttt)
            acc[oo][ttt] += w8[oo] * hv[k + ttt];
      }
    }
  }

  float ps[8], pss[8];
  #pragma unroll
  for (int oo = 0; oo < 8; ++oo) {
    const int o = o0 + oo;
    const float bo = b2c[o];
    float s = 0.f, sq = 0.f;
    #pragma unroll
    for (int ttt = 0; ttt < 8; ++ttt) {
      float v = acc[oo][ttt] + bo;
      s += v; sq += v * v;
      if (MODE == 0 && t0 == 0 && tg == 0 && ttt < 4)
        c2head[(b * NH2 + o) * 4 + ttt] = v;
    }
    ps[oo] = s; pss[oo] = sq;
  }

  __syncthreads();
  float* red = h1s;                           // reuse (4096 floats)
  #pragma unroll
  for (int oo = 0; oo < 8; ++oo) {
    red[(o0 + oo) * 16 + tg] = ps[oo];
    red[2048 + (o0 + oo) * 16 + tg] = pss[oo];
  }
  __syncthreads();
  {
    int o = threadIdx.x & 127, which = threadIdx.x >> 7;
    const float* r = &red[which * 2048 + o * 16];
    float s = 0.f;
    #pragma unroll
    for (int j = 0; j < 16; ++j) s += r[j];
    partials[blockIdx.x * 256 + which * 128 + o] = s;
  }
}

// ---------------------------------------------------------------------------
// Kernel 5: bn2+lrelu on c2 head, conv3 at t=0, tanh -> HRTF gather * dist.
// ---------------------------------------------------------------------------
__global__ __launch_bounds__(256) void finalize_spatial(
    const float* __restrict__ coef2, const float* __restrict__ c2head,
    const float* __restrict__ W3c, const float* __restrict__ b3c,
    const float* __restrict__ hrtf, float* __restrict__ wgbuf)
{
  __shared__ float h2l[NB * NH2 * 4];
  __shared__ float sp[NB * 6];
  for (int e = threadIdx.x; e < NB * NH2 * 4; e += 256) {
    int c = (e >> 2) & 127;
    h2l[e] = lrelu(coef2[c] * c2head[e] + coef2[NH2 + c]);
  }
  __syncthreads();
  if (threadIdx.x < 48) {
    int b = threadIdx.x / 6, c3 = threadIdx.x % 6;
    float acc = b3c[c3];
    for (int c = 0; c < NH2; ++c)
      #pragma unroll
      for (int k = 3; k < 7; ++k)   // t=0 sees h2[-3..3]; k<3 taps hit zeros
        acc += h2l[(b * NH2 + c) * 4 + (k - 3)] * W3c[c3 * (NH2 * 7) + c * 7 + k];
    sp[b * 6 + c3] = tanhf(acc);
  }
  __syncthreads();
  if (threadIdx.x < 16) {
    int b = threadIdx.x >> 1, i = threadIdx.x & 1;
    float az = (sp[b * 6 + i * 3 + 0] + 1.f) * 0.5f * 11.f;
    float el = (sp[b * 6 + i * 3 + 1] + 1.f) * 0.5f * 4.f;
    float dist = (sp[b * 6 + i * 3 + 2] + 1.f) * 0.5f * 0.9f + 0.1f;
    int azi = min(max((int)az, 0), 11);
    int eli = min(max((int)el, 0), 4);
    int idx = eli * 12 + azi;
    for (int e = 0; e < 14; ++e)
      wgbuf[(b * 2 + i) * 14 + e] = hrtf[idx * 14 + e] * dist;
  }
}

// ---------------------------------------------------------------------------
// Kernel 6: summed[b,c,t] = sum_{i,k} x[b,i,t+k-3] * wg[b,i,c,k]  (wg has dist)
// ---------------------------------------------------------------------------
__global__ __launch_bounds__(256) void mix_kernel(
    const float* __restrict__ x, const float* __restrict__ wgbuf,
    float* __restrict__ summed)
{
  const int b = blockIdx.x >> 7;
  const int t0 = (blockIdx.x & 127) * 1024 + threadIdx.x * 4;
  float wv[2][2][7];
  #pragma unroll
  for (int i = 0; i < 2; ++i)
    #pragma unroll
    for (int c = 0; c < 2; ++c)
      #pragma unroll
      for (int k = 0; k < 7; ++k)
        wv[i][c][k] = wgbuf[(b * 2 + i) * 14 + c * 7 + k];
  float acc[2][4] = {{0.f, 0.f, 0.f, 0.f}, {0.f, 0.f, 0.f, 0.f}};
  #pragma unroll
  for (int i = 0; i < 2; ++i) {
    float xl[12];
    #pragma unroll
    for (int j = 0; j < 12; ++j) {
      int tg = t0 - 4 + j;
      xl[j] = (tg >= 0 && tg < TLEN) ? x[(b * 2 + i) * TLEN + tg] : 0.f;
    }
    #pragma unroll
    for (int c = 0; c < 2; ++c)
      #pragma unroll
      for (int k = 0; k < 7; ++k)
        #pragma unroll
        for (int tt = 0; tt < 4; ++tt)
          acc[c][tt] += xl[tt + k + 1] * wv[i][c][k];
  }
  #pragma unroll
  for (int c = 0; c < 2; ++c)
    *reinterpret_cast<float4*>(&summed[(b * 2 + c) * TLEN + t0]) =
        make_float4(acc[c][0], acc[c][1], acc[c][2], acc[c][3]);
}

// ---------------------------------------------------------------------------
// Kernel 11: 64-col tile, all fp32. Recompute h1 (86 cols) + conv2 (80 cols),
// bn2+lrelu -> fp32 h2 LDS (aliased), conv3 (128->2, K=7) + tanh -> out.
// Static LDS: 10304 floats = 41,216 B.
// ---------------------------------------------------------------------------
__global__ __launch_bounds__(256) void conv2_final(
    const float* __restrict__ xin,
    const float* __restrict__ W1c, const float* __restrict__ b1c,
    const float* __restrict__ coef1,
    const float* __restrict__ W2c, const float* __restrict__ b2c,
    const float* __restrict__ coef2,
    const float* __restrict__ W3c, const float* __restrict__ b3c,
    float* __restrict__ out)
{
  const int b  = blockIdx.x >> 11;            // TLEN/64 = 2048 chunks
  const int t0 = (blockIdx.x & 2047) * 64;

  __shared__ float smem[10304];
  float* xs  = smem;                          // 2 x 96, col p <-> t0-14+p
  float* w1s = smem + 192;                    // 896
  float* h1s = smem + 1088;                   // 64 x 88, col m <-> t0-11+m (86 used)
  float* w2s = smem + 6720;                   // 28 x 128
  float* h2s = smem;                          // 128 x 80, col j <-> t0-8+j (aliased)
  float* red = smem;                          // 1024 (aliased, after h2 reads)

  for (int e = threadIdx.x; e < 2 * 96; e += 256) {
    int i = e / 96, p = e % 96;
    int tg = t0 - 14 + p;
    xs[e] = (tg >= 0 && tg < TLEN) ? xin[(b * NICH + i) * TLEN + tg] : 0.f;
  }
  for (int e = threadIdx.x; e < NHID * 14; e += 256) w1s[e] = W1c[e];
  __syncthreads();

  // h1 tile: 64 ch x 22 quads (88 slots, cols 0..85 meaningful)
  for (int e = threadIdx.x; e < NHID * 22; e += 256) {
    int i = e / 22, q = (e % 22) * 4;
    const float a1 = coef1[i], d1 = coef1[NHID + i];
    const float bo = b1c[i];
    float a4[2][10];
    #pragma unroll
    for (int i2 = 0; i2 < 2; ++i2) {
      const float* xp = &xs[i2 * 96 + q];
      float4 v0 = *reinterpret_cast<const float4*>(xp);
      float4 v1 = *reinterpret_cast<const float4*>(xp + 4);
      float2 v2 = *reinterpret_cast<const float2*>(xp + 8);
      a4[i2][0] = v0.x; a4[i2][1] = v0.y; a4[i2][2] = v0.z; a4[i2][3] = v0.w;
      a4[i2][4] = v1.x; a4[i2][5] = v1.y; a4[i2][6] = v1.z; a4[i2][7] = v1.w;
      a4[i2][8] = v2.x; a4[i2][9] = v2.y;
    }
    float out4[4];
    #pragma unroll
    for (int tq = 0; tq < 4; ++tq) {
      int v = t0 - 11 + q + tq;
      float acc = bo;
      #pragma unroll
      for (int i2 = 0; i2 < 2; ++i2)
        #pragma unroll
        for (int k = 0; k < 7; ++k)
          acc += a4[i2][tq + k] * w1s[i * 14 + i2 * 7 + k];
      float h = lrelu(a1 * acc + d1);
      out4[tq] = (v >= 0 && v < TLEN) ? h : 0.f;
    }
    *reinterpret_cast<float4*>(&h1s[i * 88 + q]) =
        make_float4(out4[0], out4[1], out4[2], out4[3]);
  }
  __syncthreads();

  // conv2: 16 o-groups x 8 ch, 16 t-groups x 5 cols (h2 cols j0..j0+4)
  const int og = threadIdx.x & 15, tg = threadIdx.x >> 4;
  const int o0 = og * 8, j0 = tg * 5;

  float acc[8][5];
  #pragma unroll
  for (int a = 0; a < 8; ++a)
    #pragma unroll
    for (int q = 0; q < 5; ++q) acc[a][q] = 0.f;

  for (int ic = 0; ic < NHID; ic += 4) {
    __syncthreads();
    for (int e = threadIdx.x; e < 4 * 7 * 128; e += 256) {
      int o = e & 127, kk = e >> 7;
      w2s[e] = W2c[o * (NHID * 7) + ic * 7 + kk];
    }
    __syncthreads();
    #pragma unroll
    for (int i2 = 0; i2 < 4; ++i2) {
      float hv[11];
      #pragma unroll
      for (int j = 0; j < 11; ++j) hv[j] = h1s[(ic + i2) * 88 + j0 + j];
      #pragma unroll
      for (int k = 0; k < 7; ++k) {
        float w8[8];
        #pragma unroll
        for (int oo = 0; oo < 8; ++oo) w8[oo] = w2s[(i2 * 7 + k) * 128 + o0 + oo];
        #pragma unroll
        for (int oo = 0; oo < 8; ++oo)
          #pragma unroll
          for (int tt = 0; tt < 5; ++tt)
            acc[oo][tt] += w8[oo] * hv[k + tt];
      }
    }
  }
  __syncthreads();   // all h1s/w2s reads done; smem becomes fp32 h2s

  #pragma unroll
  for (int oo = 0; oo < 8; ++oo) {
    const int o = o0 + oo;
    const float a2 = coef2[o], d2 = coef2[NH2 + o];
    const float bo = b2c[o];
    #pragma unroll
    for (int tt = 0; tt < 5; ++tt) {
      int u = t0 - 8 + j0 + tt;
      float v = lrelu(a2 * (acc[oo][tt] + bo) + d2);
      h2s[o * 80 + j0 + tt] = (u >= 0 && u < TLEN) ? v : 0.f;
    }
  }
  __syncthreads();

  // conv3: 8 ic-groups x (2 outch x 16 t-groups of 4 cols)
  const int ig  = threadIdx.x >> 5;
  const int rem = threadIdx.x & 31;
  const int c   = rem >> 4;
  const int tg2 = rem & 15;
  float acc3[4] = {0.f, 0.f, 0.f, 0.f};
  for (int i = ig * 16; i < ig * 16 + 16; ++i) {
    float hv3[10];
    const float* hp = &h2s[i * 80 + tg2 * 4 + 5];
    #pragma unroll
    for (int s = 0; s < 10; ++s) hv3[s] = hp[s];
    float wv[7];
    #pragma unroll
    for (int k = 0; k < 7; ++k) wv[k] = W3c[(c * NH2 + i) * 7 + k];
    #pragma unroll
    for (int k = 0; k < 7; ++k)
      #pragma unroll
      for (int tt = 0; tt < 4; ++tt)
        acc3[tt] += hv3[tt + k] * wv[k];
  }
  __syncthreads();   // h2s reads done; smem becomes red
  #pragma unroll
  for (int tt = 0; tt < 4; ++tt)
    red[((c * 16 + tg2) * 4 + tt) * 8 + ig] = acc3[tt];
  __syncthreads();
  if (threadIdx.x < 128) {
    int c2i = threadIdx.x >> 6, tl = threadIdx.x & 63;
    const float* r = &red[((c2i * 16 + (tl >> 2)) * 4 + (tl & 3)) * 8];
    float s = b3c[c2i];
    #pragma unroll
    for (int j = 0; j < 8; ++j) s += r[j];
    out[(b * 2 + c2i) * TLEN + t0 + tl] = tanhf(s);
  }
}

// ---------------------------------------------------------------------------
extern "C" void kernel_launch(void* const* d_in, const int* in_sizes, int n_in,
                              void* d_out, int out_size, void* d_ws, size_t ws_size,
                              hipStream_t stream)
{
  (void)in_sizes; (void)n_in; (void)out_size; (void)ws_size;
  const float* x    = (const float*)d_in[0];
  const float* W1   = (const float*)d_in[1];
  const float* b1   = (const float*)d_in[2];
  const float* g1   = (const float*)d_in[3];
  const float* be1  = (const float*)d_in[4];
  const float* W2   = (const float*)d_in[5];
  const float* b2   = (const float*)d_in[6];
  const float* g2   = (const float*)d_in[7];
  const float* be2  = (const float*)d_in[8];
  const float* W3   = (const float*)d_in[9];
  const float* b3   = (const float*)d_in[10];
  const float* hrtf = (const float*)d_in[11];
  const float* RW1  = (const float*)d_in[12];
  const float* rb1  = (const float*)d_in[13];
  const float* rg1  = (const float*)d_in[14];
  const float* rbe1 = (const float*)d_in[15];
  const float* RW2  = (const float*)d_in[16];
  const float* rb2  = (const float*)d_in[17];
  const float* rg2  = (const float*)d_in[18];
  const float* rbe2 = (const float*)d_in[19];
  const float* RW3  = (const float*)d_in[20];
  const float* rb3  = (const float*)d_in[21];
  float* out = (float*)d_out;

  // d_out doubles as the 8192x256-float stats-partials buffer; its scratch
  // lifetime (kernels 3-4 and 9-10) ends before conv2_final writes output.
  float* partialsB = (float*)d_out;

  char* ws = (char*)d_ws;
  float* partialsA = (float*)(ws + 0);        // 1024*128 f = 524,288 B
  float* summed    = (float*)(ws + 524288);   // 2,097,152 f = 8,388,608 B
  float* coef1     = (float*)(ws + 8912896);  // 128 f
  float* coef2     = (float*)(ws + 8913408);  // 256 f
  float* coefR1    = (float*)(ws + 8914432);  // 128 f
  float* coefR2    = (float*)(ws + 8914944);  // 256 f
  float* c2head    = (float*)(ws + 8915968);  // 4096 f
  float* wgbuf     = (float*)(ws + 8932352);  // 224 f
  // total ws use: 8,933,248 bytes

  // ---- spatial parameter network ----
  conv1_stats<<<1024, 256, 0, stream>>>(x, W1, b1, partialsA);
  reduce_coef<<<64, 256, 0, stream>>>(partialsA, 1024, 64, g1, be1, coef1);
  conv2_big<0><<<8192, 256, 0, stream>>>(x, W1, b1, coef1, W2, b2,
                                         partialsB, c2head);
  reduce_coef<<<128, 256, 0, stream>>>(partialsB, 8192, 128, g2, be2, coef2);
  finalize_spatial<<<1, 256, 0, stream>>>(coef2, c2head, W3, b3, hrtf, wgbuf);
  // ---- HRTF mixing ----
  mix_kernel<<<1024, 256, 0, stream>>>(x, wgbuf, summed);
  // ---- binaural renderer ----
  conv1_stats<<<1024, 256, 0, stream>>>(summed, RW1, rb1, partialsA);
  reduce_coef<<<64, 256, 0, stream>>>(partialsA, 1024, 64, rg1, rbe1, coefR1);
  conv2_big<1><<<8192, 256, 0, stream>>>(summed, RW1, rb1, coefR1, RW2, rb2,
                                         partialsB, nullptr);
  reduce_coef<<<128, 256, 0, stream>>>(partialsB, 8192, 128, rg2, rbe2, coefR2);
  conv2_final<<<16384, 256, 0, stream>>>(summed, RW1, rb1, coefR1, RW2, rb2,
                                         coefR2, RW3, rb3, out);
}

// Round 4
// 1879.595 us; speedup vs baseline: 3.5479x; 3.5479x over previous
//
#include <hip/hip_runtime.h>
#include <cstddef>

// ---------------------------------------------------------------------------
// SpatialAudioRenderer on MI355X — v4: conv2 on MFMA (split-bf16, fp32-exact).
//
// R2 counters: 3 fused conv2 kernels = 93% of 6.67 ms, MfmaUtil 0, VALUBusy
// 45-65%, LDS conflicts 1.7-3.8e8. v4 moves conv2 to 16x16x32 bf16 MFMA with
// hi/lo split (3 MFMAs per K-chunk -> ~1e-5 rel error, keeps absmax ~4e-3).
//
// Pipeline (12 launches):
//  0. split_w2                  -> W2/RW2 reordered+split bf16 (K = tap*64+ch)
//  1. conv1_stats (x)           -> partialsA
//  2. reduce_coef               -> coef1
//  3. conv2_stats_mfma (spat.)  -> partialsB(d_out)
//  4. reduce_coef               -> coef2
//  5. finalize_spatial          -> fp32 c2head recompute + HRTF gather*dist
//  6. mix_kernel                -> summed
//  7. conv1_stats (summed)      -> partialsA
//  8. reduce_coef               -> coefR1
//  9. conv2_stats_mfma (rend.)  -> partialsB(d_out)
// 10. reduce_coef               -> coefR2
// 11. conv2_final_mfma          -> conv2(MFMA) + bn2+lrelu + conv3 + tanh
// ---------------------------------------------------------------------------

#define TLEN 131072
#define NB 8
#define NICH 2
#define NHID 64
#define NH2 128
#define EPSV 1e-5f
#define CNTF 1048576.0f  // NB * TLEN

typedef short bf16x8 __attribute__((ext_vector_type(8)));
typedef float f32x4 __attribute__((ext_vector_type(4)));

__device__ __forceinline__ unsigned short f2bf(float f) {
  unsigned u = __float_as_uint(f);
  unsigned r = u + 0x7fffu + ((u >> 16) & 1u);
  return (unsigned short)(r >> 16);
}
__device__ __forceinline__ float bfl(unsigned u) { return __uint_as_float(u << 16); }
__device__ __forceinline__ float lrelu(float v) { return v >= 0.f ? v : 0.2f * v; }

// ---------------------------------------------------------------------------
// Kernel 0: reorder W2/RW2 (o,i,k)->[o][k*64+i] and split into bf16 hi+lo.
// ---------------------------------------------------------------------------
__global__ __launch_bounds__(256) void split_w2(
    const float* __restrict__ W2c, const float* __restrict__ RW2c,
    unsigned short* __restrict__ sph, unsigned short* __restrict__ spl,
    unsigned short* __restrict__ reh, unsigned short* __restrict__ rel)
{
  int e = blockIdx.x * 256 + threadIdx.x;
  if (e >= NH2 * 448) return;
  int o = e / 448, K = e % 448, k = K >> 6, i = K & 63;
  float w = W2c[(o * 64 + i) * 7 + k];
  unsigned short h = f2bf(w);
  sph[e] = h; spl[e] = f2bf(w - bfl(h));
  w = RW2c[(o * 64 + i) * 7 + k];
  h = f2bf(w);
  reh[e] = h; rel[e] = f2bf(w - bfl(h));
}

// ---------------------------------------------------------------------------
// Kernel 1/7: conv1 (Cin=2, Cout=64, K=7, SAME) -> per-block channel sum/sumsq.
// ---------------------------------------------------------------------------
#define TCH1 1024
__global__ __launch_bounds__(256) void conv1_stats(
    const float* __restrict__ x, const float* __restrict__ W,
    const float* __restrict__ bias, float* __restrict__ partials)
{
  const int b = blockIdx.x >> 7;
  const int t0 = (blockIdx.x & 127) * TCH1;
  __shared__ float xs[2 * 1032];
  __shared__ float red[512];

  for (int i = 0; i < 2; ++i)
    for (int j = threadIdx.x; j < TCH1 + 6; j += 256) {
      int tg = t0 - 3 + j;
      xs[i * 1032 + j] = (tg >= 0 && tg < TLEN) ? x[(b * NICH + i) * TLEN + tg] : 0.f;
    }
  __syncthreads();

  const int o = threadIdx.x & 63;
  const int sub = threadIdx.x >> 6;
  float w[14];
  #pragma unroll
  for (int j = 0; j < 14; ++j) w[j] = W[o * 14 + j];
  const float bo = bias[o];

  float s = 0.f, ss = 0.f;
  const int tbeg = sub * (TCH1 / 4), tend = tbeg + TCH1 / 4;
  for (int tt = tbeg; tt < tend; tt += 4) {
    float a4[2][10];
    #pragma unroll
    for (int i = 0; i < 2; ++i) {
      const float* xp = &xs[i * 1032 + tt];
      float4 v0 = *reinterpret_cast<const float4*>(xp);
      float4 v1 = *reinterpret_cast<const float4*>(xp + 4);
      float2 v2 = *reinterpret_cast<const float2*>(xp + 8);
      a4[i][0] = v0.x; a4[i][1] = v0.y; a4[i][2] = v0.z; a4[i][3] = v0.w;
      a4[i][4] = v1.x; a4[i][5] = v1.y; a4[i][6] = v1.z; a4[i][7] = v1.w;
      a4[i][8] = v2.x; a4[i][9] = v2.y;
    }
    #pragma unroll
    for (int tq = 0; tq < 4; ++tq) {
      float acc = bo;
      #pragma unroll
      for (int i = 0; i < 2; ++i)
        #pragma unroll
        for (int k = 0; k < 7; ++k)
          acc += a4[i][tq + k] * w[i * 7 + k];
      s += acc; ss += acc * acc;
    }
  }
  red[o * 4 + sub] = s;
  red[(64 + o) * 4 + sub] = ss;
  __syncthreads();
  if (threadIdx.x < 128) {
    const float* r = &red[threadIdx.x * 4];
    partials[blockIdx.x * 128 + threadIdx.x] = r[0] + r[1] + r[2] + r[3];
  }
}

// ---------------------------------------------------------------------------
// Kernel 2: reduce partials -> bn affine coefs.
// ---------------------------------------------------------------------------
__global__ __launch_bounds__(256) void reduce_coef(
    const float* __restrict__ partials, int nblocks, int C,
    const float* __restrict__ g, const float* __restrict__ be,
    float* __restrict__ coef)
{
  const int c = blockIdx.x;
  float s = 0.f, ss = 0.f;
  for (int j = threadIdx.x; j < nblocks; j += 256) {
    s  += partials[j * 2 * C + c];
    ss += partials[j * 2 * C + C + c];
  }
  #pragma unroll
  for (int off = 32; off >= 1; off >>= 1) {
    s  += __shfl_down(s, off, 64);
    ss += __shfl_down(ss, off, 64);
  }
  __shared__ float rs[4], rss[4];
  const int lane = threadIdx.x & 63, wv = threadIdx.x >> 6;
  if (lane == 0) { rs[wv] = s; rss[wv] = ss; }
  __syncthreads();
  if (threadIdx.x == 0) {
    float st  = rs[0] + rs[1] + rs[2] + rs[3];
    float sst = rss[0] + rss[1] + rss[2] + rss[3];
    float mean = st / CNTF;
    float var  = sst / CNTF - mean * mean;
    float a = g[c] * rsqrtf(var + EPSV);
    coef[c] = a;
    coef[C + c] = be[c] - mean * a;
  }
}

// ---------------------------------------------------------------------------
// Kernel 3/9: conv2 via split-bf16 MFMA, stats only (no c2 store).
// Block: 128 o x 128 t. 4 waves, each 2 M-tiles x 8 N-tiles.
// ---------------------------------------------------------------------------
__global__ __launch_bounds__(256) void conv2_stats_mfma(
    const float* __restrict__ xin,
    const float* __restrict__ W1c, const float* __restrict__ b1c,
    const float* __restrict__ coef1,
    const unsigned short* __restrict__ w2hi,
    const unsigned short* __restrict__ w2lo,
    const float* __restrict__ b2c,
    float* __restrict__ partials)
{
  const int b  = blockIdx.x >> 10;
  const int t0 = (blockIdx.x & 1023) * 128;

  __shared__ __align__(16) char smem[43328];
  short* h1hi = (short*)smem;                 // [134][72], row r <-> t0-3+r
  short* h1lo = (short*)(smem + 19296);
  float* xs   = (float*)(smem + 38592);       // [2][144], j <-> t0-6+j
  float* w1s  = (float*)(smem + 39744);       // [64][14]
  float* redS = (float*)smem;                 // [128][16] (aliases h1hi, late)
  float* redSS= (float*)(smem + 8192);

  for (int e = threadIdx.x; e < 2 * 144; e += 256) {
    int i = e / 144, j = e % 144;
    int tg = t0 - 6 + j;
    xs[e] = (tg >= 0 && tg < TLEN) ? xin[(b * NICH + i) * TLEN + tg] : 0.f;
  }
  for (int e = threadIdx.x; e < 64 * 14; e += 256) w1s[e] = W1c[e];
  __syncthreads();

  // h1 transposed tile (hi/lo bf16): 134 rows x 64 ch (stride 72)
  for (int e = threadIdx.x; e < 134 * 16; e += 256) {
    int r = e >> 4, cg = e & 15;
    int t = t0 - 3 + r;
    bool ok = (t >= 0) && (t < TLEN);
    float a[2][7];
    #pragma unroll
    for (int i2 = 0; i2 < 2; ++i2)
      #pragma unroll
      for (int k = 0; k < 7; ++k) a[i2][k] = xs[i2 * 144 + r + k];
    unsigned hs[4], ls[4];
    #pragma unroll
    for (int cc = 0; cc < 4; ++cc) {
      int ch = cg * 4 + cc;
      float acc = b1c[ch];
      #pragma unroll
      for (int i2 = 0; i2 < 2; ++i2)
        #pragma unroll
        for (int k = 0; k < 7; ++k) acc += a[i2][k] * w1s[ch * 14 + i2 * 7 + k];
      float v = lrelu(coef1[ch] * acc + coef1[64 + ch]);
      if (!ok) v = 0.f;
      unsigned short h = f2bf(v);
      hs[cc] = h;
      ls[cc] = f2bf(v - bfl(h));
    }
    *(uint2*)(h1hi + r * 72 + cg * 4) =
        make_uint2(hs[0] | (hs[1] << 16), hs[2] | (hs[3] << 16));
    *(uint2*)(h1lo + r * 72 + cg * 4) =
        make_uint2(ls[0] | (ls[1] << 16), ls[2] | (ls[3] << 16));
  }
  __syncthreads();

  const int lane = threadIdx.x & 63;
  const int wv = threadIdx.x >> 6;
  const int mn = lane & 15, quad = lane >> 4;
  const int o0w = wv * 32;

  f32x4 acc[2][8];
  #pragma unroll
  for (int mt = 0; mt < 2; ++mt)
    #pragma unroll
    for (int nt = 0; nt < 8; ++nt) {
      f32x4 z = {0.f, 0.f, 0.f, 0.f};
      acc[mt][nt] = z;
    }

  float b2v[2][4];
  #pragma unroll
  for (int mt = 0; mt < 2; ++mt)
    #pragma unroll
    for (int r = 0; r < 4; ++r)
      b2v[mt][r] = b2c[o0w + mt * 16 + quad * 4 + r];

  bf16x8 cah[2], cal[2], nah[2], nal[2];
  auto loadA = [&](int c, bf16x8 (&H)[2], bf16x8 (&L)[2]) {
    #pragma unroll
    for (int mt = 0; mt < 2; ++mt) {
      int off = (o0w + mt * 16 + mn) * 448 + c * 32 + quad * 8;
      H[mt] = *(const bf16x8*)(w2hi + off);
      L[mt] = *(const bf16x8*)(w2lo + off);
    }
  };
  loadA(0, cah, cal);
  for (int c = 0; c < 14; ++c) {
    if (c < 13) loadA(c + 1, nah, nal);
    const int tap = c >> 1;
    const int ch0 = (c & 1) * 32 + quad * 8;
    #pragma unroll
    for (int nt = 0; nt < 8; ++nt) {
      const int row = nt * 16 + mn + tap;
      bf16x8 bh = *(const bf16x8*)(h1hi + row * 72 + ch0);
      bf16x8 bl = *(const bf16x8*)(h1lo + row * 72 + ch0);
      acc[0][nt] = __builtin_amdgcn_mfma_f32_16x16x32_bf16(cah[0], bh, acc[0][nt], 0, 0, 0);
      acc[1][nt] = __builtin_amdgcn_mfma_f32_16x16x32_bf16(cah[1], bh, acc[1][nt], 0, 0, 0);
      acc[0][nt] = __builtin_amdgcn_mfma_f32_16x16x32_bf16(cal[0], bh, acc[0][nt], 0, 0, 0);
      acc[1][nt] = __builtin_amdgcn_mfma_f32_16x16x32_bf16(cal[1], bh, acc[1][nt], 0, 0, 0);
      acc[0][nt] = __builtin_amdgcn_mfma_f32_16x16x32_bf16(cah[0], bl, acc[0][nt], 0, 0, 0);
      acc[1][nt] = __builtin_amdgcn_mfma_f32_16x16x32_bf16(cah[1], bl, acc[1][nt], 0, 0, 0);
    }
    cah[0] = nah[0]; cah[1] = nah[1]; cal[0] = nal[0]; cal[1] = nal[1];
  }
  __syncthreads();   // h1 tiles dead; smem becomes reduction buffers

  #pragma unroll
  for (int mt = 0; mt < 2; ++mt)
    #pragma unroll
    for (int r = 0; r < 4; ++r) {
      float s = 0.f, ss = 0.f;
      #pragma unroll
      for (int nt = 0; nt < 8; ++nt) {
        float v = acc[mt][nt][r] + b2v[mt][r];
        s += v; ss += v * v;
      }
      int o = o0w + mt * 16 + quad * 4 + r;
      redS[o * 16 + mn] = s;
      redSS[o * 16 + mn] = ss;
    }
  __syncthreads();
  {
    int o = threadIdx.x & 127;
    const float* src = (threadIdx.x < 128) ? redS : redSS;
    float s = 0.f;
    #pragma unroll
    for (int j = 0; j < 16; ++j) s += src[o * 16 + j];
    partials[blockIdx.x * 256 + threadIdx.x] = s;
  }
}

// ---------------------------------------------------------------------------
// Kernel 5: fp32 recompute of c2[t=0..3] head + bn2 + conv3(t=0) + tanh ->
// az/el/dist -> HRTF gather * dist. One block.
// ---------------------------------------------------------------------------
__global__ __launch_bounds__(256) void finalize_spatial(
    const float* __restrict__ x,
    const float* __restrict__ W1c, const float* __restrict__ b1c,
    const float* __restrict__ coef1,
    const float* __restrict__ W2c, const float* __restrict__ b2c,
    const float* __restrict__ coef2,
    const float* __restrict__ W3c, const float* __restrict__ b3c,
    const float* __restrict__ hrtf, float* __restrict__ wgbuf)
{
  __shared__ float xl[NB * 2 * 16];    // j <-> t = j-6 (zeros for t<0)
  __shared__ float h1l[NB * 64 * 10];  // tt <-> t = tt-3
  __shared__ float h2l[NB * NH2 * 4];
  __shared__ float sp[48];
  const int tid = threadIdx.x;
  {
    int bb = tid >> 5, i = (tid >> 4) & 1, j = tid & 15;
    int t = j - 6;
    xl[tid] = (t >= 0) ? x[(bb * 2 + i) * TLEN + t] : 0.f;
  }
  __syncthreads();
  for (int e = tid; e < NB * 64; e += 256) {
    int bb = e >> 6, ch = e & 63;
    float a1 = coef1[ch], d1 = coef1[64 + ch], bo = b1c[ch];
    for (int tt = 0; tt < 10; ++tt) {
      float acc = bo;
      #pragma unroll
      for (int i2 = 0; i2 < 2; ++i2)
        #pragma unroll
        for (int k = 0; k < 7; ++k)
          acc += xl[(bb * 2 + i2) * 16 + tt + k] * W1c[ch * 14 + i2 * 7 + k];
      float v = lrelu(a1 * acc + d1);
      h1l[(bb * 64 + ch) * 10 + tt] = (tt >= 3) ? v : 0.f;
    }
  }
  __syncthreads();
  for (int e = tid; e < NB * NH2; e += 256) {
    int bb = e >> 7, o = e & 127;
    float a2 = coef2[o], d2 = coef2[NH2 + o], bo = b2c[o];
    float acc[4] = {bo, bo, bo, bo};
    for (int i = 0; i < 64; ++i)
      #pragma unroll
      for (int k = 0; k < 7; ++k) {
        float w = W2c[(o * 64 + i) * 7 + k];
        #pragma unroll
        for (int t = 0; t < 4; ++t)
          acc[t] += h1l[(bb * 64 + i) * 10 + t + k] * w;
      }
    #pragma unroll
    for (int t = 0; t < 4; ++t)
      h2l[(bb * NH2 + o) * 4 + t] = lrelu(a2 * acc[t] + d2);
  }
  __syncthreads();
  if (tid < 48) {
    int bb = tid / 6, c3 = tid % 6;
    float acc = b3c[c3];
    for (int c = 0; c < NH2; ++c)
      #pragma unroll
      for (int k = 3; k < 7; ++k)
        acc += h2l[(bb * NH2 + c) * 4 + (k - 3)] * W3c[(c3 * NH2 + c) * 7 + k];
    sp[tid] = tanhf(acc);
  }
  __syncthreads();
  if (tid < 16) {
    int bb = tid >> 1, i = tid & 1;
    float az = (sp[bb * 6 + i * 3 + 0] + 1.f) * 0.5f * 11.f;
    float el = (sp[bb * 6 + i * 3 + 1] + 1.f) * 0.5f * 4.f;
    float dist = (sp[bb * 6 + i * 3 + 2] + 1.f) * 0.5f * 0.9f + 0.1f;
    int azi = min(max((int)az, 0), 11);
    int eli = min(max((int)el, 0), 4);
    int idx = eli * 12 + azi;
    for (int e = 0; e < 14; ++e)
      wgbuf[(bb * 2 + i) * 14 + e] = hrtf[idx * 14 + e] * dist;
  }
}

// ---------------------------------------------------------------------------
// Kernel 6: summed[b,c,t] = sum_{i,k} x[b,i,t+k-3] * wg[b,i,c,k]
// ---------------------------------------------------------------------------
__global__ __launch_bounds__(256) void mix_kernel(
    const float* __restrict__ x, const float* __restrict__ wgbuf,
    float* __restrict__ summed)
{
  const int b = blockIdx.x >> 7;
  const int t0 = (blockIdx.x & 127) * 1024 + threadIdx.x * 4;
  float wv[2][2][7];
  #pragma unroll
  for (int i = 0; i < 2; ++i)
    #pragma unroll
    for (int c = 0; c < 2; ++c)
      #pragma unroll
      for (int k = 0; k < 7; ++k)
        wv[i][c][k] = wgbuf[(b * 2 + i) * 14 + c * 7 + k];
  float acc[2][4] = {{0.f, 0.f, 0.f, 0.f}, {0.f, 0.f, 0.f, 0.f}};
  #pragma unroll
  for (int i = 0; i < 2; ++i) {
    float xl[12];
    #pragma unroll
    for (int j = 0; j < 12; ++j) {
      int tg = t0 - 4 + j;
      xl[j] = (tg >= 0 && tg < TLEN) ? x[(b * 2 + i) * TLEN + tg] : 0.f;
    }
    #pragma unroll
    for (int c = 0; c < 2; ++c)
      #pragma unroll
      for (int k = 0; k < 7; ++k)
        #pragma unroll
        for (int tt = 0; tt < 4; ++tt)
          acc[c][tt] += xl[tt + k + 1] * wv[i][c][k];
  }
  #pragma unroll
  for (int c = 0; c < 2; ++c)
    *reinterpret_cast<float4*>(&summed[(b * 2 + c) * TLEN + t0]) =
        make_float4(acc[c][0], acc[c][1], acc[c][2], acc[c][3]);
}

// ---------------------------------------------------------------------------
// Kernel 11: 64-col tile. conv2 via split-bf16 MFMA (5 N-tiles at t0-8),
// bn2+lrelu -> fp32 h2 LDS, conv3 (128->2) + tanh -> out.
// LDS 61,632 B (regions aliased by phase).
// ---------------------------------------------------------------------------
__global__ __launch_bounds__(256) void conv2_final_mfma(
    const float* __restrict__ xin,
    const float* __restrict__ W1c, const float* __restrict__ b1c,
    const float* __restrict__ coef1,
    const unsigned short* __restrict__ w2hi,
    const unsigned short* __restrict__ w2lo,
    const float* __restrict__ b2c, const float* __restrict__ coef2,
    const float* __restrict__ W3c, const float* __restrict__ b3c,
    float* __restrict__ out)
{
  const int b  = blockIdx.x >> 11;            // TLEN/64 = 2048 chunks
  const int t0 = (blockIdx.x & 2047) * 64;

  __shared__ __align__(16) char smem[61632];
  float* h2s  = (float*)smem;                 // [128][72], col jj <-> t0-3+jj
  float* xs   = (float*)smem;                 // [2][96] (early alias)
  float* w1s  = (float*)(smem + 768);         // [64][14] (early alias)
  short* h1hi = (short*)(smem + 36864);       // [86][72], row r <-> t0-11+r
  short* h1lo = (short*)(smem + 49248);
  float* red  = (float*)(smem + 36864);       // 1024 f (aliases h1hi, late)

  for (int e = threadIdx.x; e < 2 * 96; e += 256) {
    int i = e / 96, j = e % 96;
    int tg = t0 - 14 + j;
    xs[e] = (tg >= 0 && tg < TLEN) ? xin[(b * NICH + i) * TLEN + tg] : 0.f;
  }
  for (int e = threadIdx.x; e < 64 * 14; e += 256) w1s[e] = W1c[e];
  __syncthreads();

  for (int e = threadIdx.x; e < 86 * 16; e += 256) {
    int r = e >> 4, cg = e & 15;
    int t = t0 - 11 + r;
    bool ok = (t >= 0) && (t < TLEN);
    float a[2][7];
    #pragma unroll
    for (int i2 = 0; i2 < 2; ++i2)
      #pragma unroll
      for (int k = 0; k < 7; ++k) a[i2][k] = xs[i2 * 96 + r + k];
    unsigned hs[4], ls[4];
    #pragma unroll
    for (int cc = 0; cc < 4; ++cc) {
      int ch = cg * 4 + cc;
      float acc = b1c[ch];
      #pragma unroll
      for (int i2 = 0; i2 < 2; ++i2)
        #pragma unroll
        for (int k = 0; k < 7; ++k) acc += a[i2][k] * w1s[ch * 14 + i2 * 7 + k];
      float v = lrelu(coef1[ch] * acc + coef1[64 + ch]);
      if (!ok) v = 0.f;
      unsigned short h = f2bf(v);
      hs[cc] = h;
      ls[cc] = f2bf(v - bfl(h));
    }
    *(uint2*)(h1hi + r * 72 + cg * 4) =
        make_uint2(hs[0] | (hs[1] << 16), hs[2] | (hs[3] << 16));
    *(uint2*)(h1lo + r * 72 + cg * 4) =
        make_uint2(ls[0] | (ls[1] << 16), ls[2] | (ls[3] << 16));
  }
  __syncthreads();

  const int lane = threadIdx.x & 63;
  const int wv = threadIdx.x >> 6;
  const int mn = lane & 15, quad = lane >> 4;
  const int o0w = wv * 32;

  f32x4 acc[2][5];
  #pragma unroll
  for (int mt = 0; mt < 2; ++mt)
    #pragma unroll
    for (int nt = 0; nt < 5; ++nt) {
      f32x4 z = {0.f, 0.f, 0.f, 0.f};
      acc[mt][nt] = z;
    }

  float b2v[2][4], a2v[2][4], d2v[2][4];
  #pragma unroll
  for (int mt = 0; mt < 2; ++mt)
    #pragma unroll
    for (int r = 0; r < 4; ++r) {
      int o = o0w + mt * 16 + quad * 4 + r;
      b2v[mt][r] = b2c[o];
      a2v[mt][r] = coef2[o];
      d2v[mt][r] = coef2[NH2 + o];
    }

  bf16x8 cah[2], cal[2], nah[2], nal[2];
  auto loadA = [&](int c, bf16x8 (&H)[2], bf16x8 (&L)[2]) {
    #pragma unroll
    for (int mt = 0; mt < 2; ++mt) {
      int off = (o0w + mt * 16 + mn) * 448 + c * 32 + quad * 8;
      H[mt] = *(const bf16x8*)(w2hi + off);
      L[mt] = *(const bf16x8*)(w2lo + off);
    }
  };
  loadA(0, cah, cal);
  for (int c = 0; c < 14; ++c) {
    if (c < 13) loadA(c + 1, nah, nal);
    const int tap = c >> 1;
    const int ch0 = (c & 1) * 32 + quad * 8;
    #pragma unroll
    for (int nt = 0; nt < 5; ++nt) {
      const int row = nt * 16 + mn + tap;
      bf16x8 bh = *(const bf16x8*)(h1hi + row * 72 + ch0);
      bf16x8 bl = *(const bf16x8*)(h1lo + row * 72 + ch0);
      acc[0][nt] = __builtin_amdgcn_mfma_f32_16x16x32_bf16(cah[0], bh, acc[0][nt], 0, 0, 0);
      acc[1][nt] = __builtin_amdgcn_mfma_f32_16x16x32_bf16(cah[1], bh, acc[1][nt], 0, 0, 0);
      acc[0][nt] = __builtin_amdgcn_mfma_f32_16x16x32_bf16(cal[0], bh, acc[0][nt], 0, 0, 0);
      acc[1][nt] = __builtin_amdgcn_mfma_f32_16x16x32_bf16(cal[1], bh, acc[1][nt], 0, 0, 0);
      acc[0][nt] = __builtin_amdgcn_mfma_f32_16x16x32_bf16(cah[0], bl, acc[0][nt], 0, 0, 0);
      acc[1][nt] = __builtin_amdgcn_mfma_f32_16x16x32_bf16(cah[1], bl, acc[1][nt], 0, 0, 0);
    }
    cah[0] = nah[0]; cah[1] = nah[1]; cal[0] = nal[0]; cal[1] = nal[1];
  }
  __syncthreads();   // h1 tiles + xs/w1s dead

  // bn2 + lrelu -> fp32 h2 (cols jj = j-5, j in [5,75))
  #pragma unroll
  for (int mt = 0; mt < 2; ++mt)
    #pragma unroll
    for (int nt = 0; nt < 5; ++nt) {
      int j = nt * 16 + mn;
      int t = t0 - 8 + j;
      if (j >= 5 && j < 75) {
        #pragma unroll
        for (int r = 0; r < 4; ++r) {
          float v = acc[mt][nt][r] + b2v[mt][r];
          v = lrelu(a2v[mt][r] * v + d2v[mt][r]);
          int o = o0w + mt * 16 + quad * 4 + r;
          h2s[o * 72 + (j - 5)] = (t >= 0 && t < TLEN) ? v : 0.f;
        }
      }
    }
  __syncthreads();

  // conv3: 8 ic-groups x (2 outch x 16 t-groups of 4)
  const int ig  = threadIdx.x >> 5;
  const int rem = threadIdx.x & 31;
  const int c2  = rem >> 4;
  const int tg2 = rem & 15;
  float acc3[4] = {0.f, 0.f, 0.f, 0.f};
  for (int i = ig * 16; i < ig * 16 + 16; ++i) {
    float hv3[10];
    const float* hp = &h2s[i * 72 + tg2 * 4];
    #pragma unroll
    for (int s = 0; s < 10; ++s) hv3[s] = hp[s];
    float wv3[7];
    #pragma unroll
    for (int k = 0; k < 7; ++k) wv3[k] = W3c[(c2 * NH2 + i) * 7 + k];
    #pragma unroll
    for (int k = 0; k < 7; ++k)
      #pragma unroll
      for (int tt = 0; tt < 4; ++tt)
        acc3[tt] += hv3[tt + k] * wv3[k];
  }
  #pragma unroll
  for (int tt = 0; tt < 4; ++tt)
    red[((c2 * 16 + tg2) * 4 + tt) * 8 + ig] = acc3[tt];
  __syncthreads();
  if (threadIdx.x < 128) {
    int c2i = threadIdx.x >> 6, tl = threadIdx.x & 63;
    const float* r = &red[((c2i * 16 + (tl >> 2)) * 4 + (tl & 3)) * 8];
    float s = b3c[c2i];
    #pragma unroll
    for (int j = 0; j < 8; ++j) s += r[j];
    out[(b * 2 + c2i) * TLEN + t0 + tl] = tanhf(s);
  }
}

// ---------------------------------------------------------------------------
extern "C" void kernel_launch(void* const* d_in, const int* in_sizes, int n_in,
                              void* d_out, int out_size, void* d_ws, size_t ws_size,
                              hipStream_t stream)
{
  (void)in_sizes; (void)n_in; (void)out_size; (void)ws_size;
  const float* x    = (const float*)d_in[0];
  const float* W1   = (const float*)d_in[1];
  const float* b1   = (const float*)d_in[2];
  const float* g1   = (const float*)d_in[3];
  const float* be1  = (const float*)d_in[4];
  const float* W2   = (const float*)d_in[5];
  const float* b2   = (const float*)d_in[6];
  const float* g2   = (const float*)d_in[7];
  const float* be2  = (const float*)d_in[8];
  const float* W3   = (const float*)d_in[9];
  const float* b3   = (const float*)d_in[10];
  const float* hrtf = (const float*)d_in[11];
  const float* RW1  = (const float*)d_in[12];
  const float* rb1  = (const float*)d_in[13];
  const float* rg1  = (const float*)d_in[14];
  const float* rbe1 = (const float*)d_in[15];
  const float* RW2  = (const float*)d_in[16];
  const float* rb2  = (const float*)d_in[17];
  const float* rg2  = (const float*)d_in[18];
  const float* rbe2 = (const float*)d_in[19];
  const float* RW3  = (const float*)d_in[20];
  const float* rb3  = (const float*)d_in[21];
  float* out = (float*)d_out;

  // d_out (2,097,152 f) doubles as the 8192x256-f stats-partials buffer;
  // its scratch lifetime ends before conv2_final_mfma writes output.
  float* partialsB = (float*)d_out;

  char* ws = (char*)d_ws;
  float* partialsA        = (float*)(ws + 0);        // 524,288 B
  float* summed           = (float*)(ws + 524288);   // 8,388,608 B
  float* coef1            = (float*)(ws + 8912896);  // 128 f
  float* coef2            = (float*)(ws + 8913408);  // 256 f
  float* coefR1           = (float*)(ws + 8914432);  // 128 f
  float* coefR2           = (float*)(ws + 8914944);  // 256 f
  float* wgbuf            = (float*)(ws + 8915968);  // 224 f
  unsigned short* w2sp_hi = (unsigned short*)(ws + 8916992);  // 114,688 B
  unsigned short* w2sp_lo = (unsigned short*)(ws + 9031680);
  unsigned short* w2re_hi = (unsigned short*)(ws + 9146368);
  unsigned short* w2re_lo = (unsigned short*)(ws + 9261056);
  // total ws use: 9,375,744 bytes

  split_w2<<<224, 256, 0, stream>>>(W2, RW2, w2sp_hi, w2sp_lo, w2re_hi, w2re_lo);
  // ---- spatial parameter network ----
  conv1_stats<<<1024, 256, 0, stream>>>(x, W1, b1, partialsA);
  reduce_coef<<<64, 256, 0, stream>>>(partialsA, 1024, 64, g1, be1, coef1);
  conv2_stats_mfma<<<8192, 256, 0, stream>>>(x, W1, b1, coef1,
                                             w2sp_hi, w2sp_lo, b2, partialsB);
  reduce_coef<<<128, 256, 0, stream>>>(partialsB, 8192, 128, g2, be2, coef2);
  finalize_spatial<<<1, 256, 0, stream>>>(x, W1, b1, coef1, W2, b2, coef2,
                                          W3, b3, hrtf, wgbuf);
  // ---- HRTF mixing ----
  mix_kernel<<<1024, 256, 0, stream>>>(x, wgbuf, summed);
  // ---- binaural renderer ----
  conv1_stats<<<1024, 256, 0, stream>>>(summed, RW1, rb1, partialsA);
  reduce_coef<<<64, 256, 0, stream>>>(partialsA, 1024, 64, rg1, rbe1, coefR1);
  conv2_stats_mfma<<<8192, 256, 0, stream>>>(summed, RW1, rb1, coefR1,
                                             w2re_hi, w2re_lo, rb2, partialsB);
  reduce_coef<<<128, 256, 0, stream>>>(partialsB, 8192, 128, rg2, rbe2, coefR2);
  conv2_final_mfma<<<16384, 256, 0, stream>>>(summed, RW1, rb1, coefR1,
                                              w2re_hi, w2re_lo, rb2, coefR2,
                                              RW3, rb3, out);
}

// Round 5
// 1459.065 us; speedup vs baseline: 4.5705x; 1.2882x over previous
//
#include <hip/hip_runtime.h>
#include <hip/hip_fp16.h>
#include <cstddef>

// ---------------------------------------------------------------------------
// SpatialAudioRenderer on MI355X — v5: single-fp16 MFMA conv2 + MFMA conv3.
//
// R4 counters: conv2_final 880us @ MfmaUtil 22%, 1.8e8 LDS conflicts (fp32 h2
// stride-72 store = structural 4-way; conv3 on VALU ~896cyc/wave). v5:
//  - fp16 single precision for conv2 A/B (3x fewer MFMAs vs split-bf16;
//    predicted absmax ~7e-3 vs 2e-2 threshold)
//  - conv3 as MFMA: h2 stored fp16 [col][ch] (B-layout, conflict-free),
//    W3 zero-padded to 16x896 fp16 A-matrix
//  - stats reduce stride 17 (was 16: 32-way read conflict)
// ---------------------------------------------------------------------------

#define TLEN 131072
#define NB 8
#define NICH 2
#define NHID 64
#define NH2 128
#define EPSV 1e-5f
#define CNTF 1048576.0f  // NB * TLEN

typedef _Float16 f16x8 __attribute__((ext_vector_type(8)));
typedef float f32x4 __attribute__((ext_vector_type(4)));

__device__ __forceinline__ float lrelu(float v) { return v >= 0.f ? v : 0.2f * v; }
__device__ __forceinline__ unsigned short h16(float v) {
  return __half_as_ushort(__float2half(v));
}

// ---------------------------------------------------------------------------
// Kernel 0: weight prep.
//  w2sp/w2re: [o][K=tap*64+ch] fp16, 128x448 each.
//  w3f:       [m][K=tap*128+ch] fp16, 16x896 (rows 2..15 zero), from RW3.
// ---------------------------------------------------------------------------
__global__ __launch_bounds__(256) void prep_weights(
    const float* __restrict__ W2c, const float* __restrict__ RW2c,
    const float* __restrict__ RW3c,
    unsigned short* __restrict__ w2sp, unsigned short* __restrict__ w2re,
    unsigned short* __restrict__ w3f)
{
  int e = blockIdx.x * 256 + threadIdx.x;
  if (e < 57344) {
    int o = e / 448, K = e % 448;
    w2sp[e] = h16(W2c[(o * 64 + (K & 63)) * 7 + (K >> 6)]);
  } else if (e < 114688) {
    int e2 = e - 57344;
    int o = e2 / 448, K = e2 % 448;
    w2re[e2] = h16(RW2c[(o * 64 + (K & 63)) * 7 + (K >> 6)]);
  } else if (e < 129024) {
    int e2 = e - 114688;
    int m = e2 / 896, K = e2 % 896;
    w3f[e2] = (m < 2) ? h16(RW3c[(m * 128 + (K & 127)) * 7 + (K >> 7)])
                      : (unsigned short)0;
  }
}

// ---------------------------------------------------------------------------
// Kernel 1/7: conv1 (Cin=2, Cout=64, K=7, SAME) -> per-block channel sum/sumsq.
// ---------------------------------------------------------------------------
#define TCH1 1024
__global__ __launch_bounds__(256) void conv1_stats(
    const float* __restrict__ x, const float* __restrict__ W,
    const float* __restrict__ bias, float* __restrict__ partials)
{
  const int b = blockIdx.x >> 7;
  const int t0 = (blockIdx.x & 127) * TCH1;
  __shared__ float xs[2 * 1032];
  __shared__ float red[512];

  for (int i = 0; i < 2; ++i)
    for (int j = threadIdx.x; j < TCH1 + 6; j += 256) {
      int tg = t0 - 3 + j;
      xs[i * 1032 + j] = (tg >= 0 && tg < TLEN) ? x[(b * NICH + i) * TLEN + tg] : 0.f;
    }
  __syncthreads();

  const int o = threadIdx.x & 63;
  const int sub = threadIdx.x >> 6;
  float w[14];
  #pragma unroll
  for (int j = 0; j < 14; ++j) w[j] = W[o * 14 + j];
  const float bo = bias[o];

  float s = 0.f, ss = 0.f;
  const int tbeg = sub * (TCH1 / 4), tend = tbeg + TCH1 / 4;
  for (int tt = tbeg; tt < tend; tt += 4) {
    float a4[2][10];
    #pragma unroll
    for (int i = 0; i < 2; ++i) {
      const float* xp = &xs[i * 1032 + tt];
      float4 v0 = *reinterpret_cast<const float4*>(xp);
      float4 v1 = *reinterpret_cast<const float4*>(xp + 4);
      float2 v2 = *reinterpret_cast<const float2*>(xp + 8);
      a4[i][0] = v0.x; a4[i][1] = v0.y; a4[i][2] = v0.z; a4[i][3] = v0.w;
      a4[i][4] = v1.x; a4[i][5] = v1.y; a4[i][6] = v1.z; a4[i][7] = v1.w;
      a4[i][8] = v2.x; a4[i][9] = v2.y;
    }
    #pragma unroll
    for (int tq = 0; tq < 4; ++tq) {
      float acc = bo;
      #pragma unroll
      for (int i = 0; i < 2; ++i)
        #pragma unroll
        for (int k = 0; k < 7; ++k)
          acc += a4[i][tq + k] * w[i * 7 + k];
      s += acc; ss += acc * acc;
    }
  }
  red[o * 4 + sub] = s;
  red[(64 + o) * 4 + sub] = ss;
  __syncthreads();
  if (threadIdx.x < 128) {
    const float* r = &red[threadIdx.x * 4];
    partials[blockIdx.x * 128 + threadIdx.x] = r[0] + r[1] + r[2] + r[3];
  }
}

// ---------------------------------------------------------------------------
// Kernel 2: reduce partials -> bn affine coefs.
// ---------------------------------------------------------------------------
__global__ __launch_bounds__(256) void reduce_coef(
    const float* __restrict__ partials, int nblocks, int C,
    const float* __restrict__ g, const float* __restrict__ be,
    float* __restrict__ coef)
{
  const int c = blockIdx.x;
  float s = 0.f, ss = 0.f;
  for (int j = threadIdx.x; j < nblocks; j += 256) {
    s  += partials[j * 2 * C + c];
    ss += partials[j * 2 * C + C + c];
  }
  #pragma unroll
  for (int off = 32; off >= 1; off >>= 1) {
    s  += __shfl_down(s, off, 64);
    ss += __shfl_down(ss, off, 64);
  }
  __shared__ float rs[4], rss[4];
  const int lane = threadIdx.x & 63, wv = threadIdx.x >> 6;
  if (lane == 0) { rs[wv] = s; rss[wv] = ss; }
  __syncthreads();
  if (threadIdx.x == 0) {
    float st  = rs[0] + rs[1] + rs[2] + rs[3];
    float sst = rss[0] + rss[1] + rss[2] + rss[3];
    float mean = st / CNTF;
    float var  = sst / CNTF - mean * mean;
    float a = g[c] * rsqrtf(var + EPSV);
    coef[c] = a;
    coef[C + c] = be[c] - mean * a;
  }
}

// ---------------------------------------------------------------------------
// Kernel 3/9: conv2 via fp16 MFMA, stats only. Block: 128 o x 128 t.
// 4 waves; wave w owns o in [w*32, w*32+32) (2 M-tiles), all 8 N-tiles.
// ---------------------------------------------------------------------------
__global__ __launch_bounds__(256) void conv2_stats_mfma(
    const float* __restrict__ xin,
    const float* __restrict__ W1c, const float* __restrict__ b1c,
    const float* __restrict__ coef1,
    const unsigned short* __restrict__ w2f,
    const float* __restrict__ b2c,
    float* __restrict__ partials)
{
  const int b  = blockIdx.x >> 10;
  const int t0 = (blockIdx.x & 1023) * 128;

  __shared__ __align__(16) char smem[24032];
  unsigned short* h1f = (unsigned short*)smem;  // [134][72], row r <-> t0-3+r
  float* xs   = (float*)(smem + 19296);         // [2][144], j <-> t0-6+j
  float* w1s  = (float*)(smem + 20448);         // [64][14]
  float* redS = (float*)smem;                   // [128][17], aliases h1f (late)
  float* redSS= (float*)(smem + 8704);

  for (int e = threadIdx.x; e < 2 * 144; e += 256) {
    int i = e / 144, j = e % 144;
    int tg = t0 - 6 + j;
    xs[e] = (tg >= 0 && tg < TLEN) ? xin[(b * NICH + i) * TLEN + tg] : 0.f;
  }
  for (int e = threadIdx.x; e < 64 * 14; e += 256) w1s[e] = W1c[e];
  __syncthreads();

  // h1 fp16 transposed tile: 134 rows x 64 ch (stride 72)
  for (int e = threadIdx.x; e < 134 * 16; e += 256) {
    int r = e >> 4, cg = e & 15;
    int t = t0 - 3 + r;
    bool ok = (t >= 0) && (t < TLEN);
    float a[2][7];
    #pragma unroll
    for (int i2 = 0; i2 < 2; ++i2)
      #pragma unroll
      for (int k = 0; k < 7; ++k) a[i2][k] = xs[i2 * 144 + r + k];
    unsigned u[4];
    #pragma unroll
    for (int cc = 0; cc < 4; ++cc) {
      int ch = cg * 4 + cc;
      float acc = b1c[ch];
      #pragma unroll
      for (int i2 = 0; i2 < 2; ++i2)
        #pragma unroll
        for (int k = 0; k < 7; ++k) acc += a[i2][k] * w1s[ch * 14 + i2 * 7 + k];
      float v = lrelu(coef1[ch] * acc + coef1[64 + ch]);
      u[cc] = h16(ok ? v : 0.f);
    }
    *(uint2*)(h1f + r * 72 + cg * 4) =
        make_uint2(u[0] | (u[1] << 16), u[2] | (u[3] << 16));
  }
  __syncthreads();

  const int lane = threadIdx.x & 63;
  const int wv = threadIdx.x >> 6;
  const int mn = lane & 15, quad = lane >> 4;
  const int o0w = wv * 32;

  f32x4 acc[2][8];
  #pragma unroll
  for (int mt = 0; mt < 2; ++mt)
    #pragma unroll
    for (int nt = 0; nt < 8; ++nt) {
      f32x4 z = {0.f, 0.f, 0.f, 0.f};
      acc[mt][nt] = z;
    }

  float b2v[2][4];
  #pragma unroll
  for (int mt = 0; mt < 2; ++mt)
    #pragma unroll
    for (int r = 0; r < 4; ++r)
      b2v[mt][r] = b2c[o0w + mt * 16 + quad * 4 + r];

  f16x8 ca[2], na[2];
  auto loadA = [&](int c, f16x8 (&A)[2]) {
    #pragma unroll
    for (int mt = 0; mt < 2; ++mt)
      A[mt] = *(const f16x8*)(w2f + (o0w + mt * 16 + mn) * 448 + c * 32 + quad * 8);
  };
  loadA(0, ca);
  for (int c = 0; c < 14; ++c) {
    if (c < 13) loadA(c + 1, na);
    const int tap = c >> 1;
    const int ch0 = (c & 1) * 32 + quad * 8;
    #pragma unroll
    for (int nt = 0; nt < 8; ++nt) {
      const int row = nt * 16 + mn + tap;
      f16x8 bb = *(const f16x8*)(h1f + row * 72 + ch0);
      acc[0][nt] = __builtin_amdgcn_mfma_f32_16x16x32_f16(ca[0], bb, acc[0][nt], 0, 0, 0);
      acc[1][nt] = __builtin_amdgcn_mfma_f32_16x16x32_f16(ca[1], bb, acc[1][nt], 0, 0, 0);
    }
    ca[0] = na[0]; ca[1] = na[1];
  }
  __syncthreads();   // h1f dead; smem becomes reduction buffers

  #pragma unroll
  for (int mt = 0; mt < 2; ++mt)
    #pragma unroll
    for (int r = 0; r < 4; ++r) {
      float s = 0.f, ss = 0.f;
      #pragma unroll
      for (int nt = 0; nt < 8; ++nt) {
        float v = acc[mt][nt][r] + b2v[mt][r];
        s += v; ss += v * v;
      }
      int o = o0w + mt * 16 + quad * 4 + r;
      redS[o * 17 + mn] = s;
      redSS[o * 17 + mn] = ss;
    }
  __syncthreads();
  {
    int o = threadIdx.x & 127;
    const float* src = (threadIdx.x < 128) ? redS : redSS;
    float s = 0.f;
    #pragma unroll
    for (int j = 0; j < 16; ++j) s += src[o * 17 + j];
    partials[blockIdx.x * 256 + threadIdx.x] = s;
  }
}

// ---------------------------------------------------------------------------
// Kernel 5: fp32 recompute of c2 head + bn2 + conv3(t=0) + tanh -> HRTF gather.
// ---------------------------------------------------------------------------
__global__ __launch_bounds__(256) void finalize_spatial(
    const float* __restrict__ x,
    const float* __restrict__ W1c, const float* __restrict__ b1c,
    const float* __restrict__ coef1,
    const float* __restrict__ W2c, const float* __restrict__ b2c,
    const float* __restrict__ coef2,
    const float* __restrict__ W3c, const float* __restrict__ b3c,
    const float* __restrict__ hrtf, float* __restrict__ wgbuf)
{
  __shared__ float xl[NB * 2 * 16];
  __shared__ float h1l[NB * 64 * 10];
  __shared__ float h2l[NB * NH2 * 4];
  __shared__ float sp[48];
  const int tid = threadIdx.x;
  {
    int bb = tid >> 5, i = (tid >> 4) & 1, j = tid & 15;
    int t = j - 6;
    xl[tid] = (t >= 0) ? x[(bb * 2 + i) * TLEN + t] : 0.f;
  }
  __syncthreads();
  for (int e = tid; e < NB * 64; e += 256) {
    int bb = e >> 6, ch = e & 63;
    float a1 = coef1[ch], d1 = coef1[64 + ch], bo = b1c[ch];
    for (int tt = 0; tt < 10; ++tt) {
      float acc = bo;
      #pragma unroll
      for (int i2 = 0; i2 < 2; ++i2)
        #pragma unroll
        for (int k = 0; k < 7; ++k)
          acc += xl[(bb * 2 + i2) * 16 + tt + k] * W1c[ch * 14 + i2 * 7 + k];
      float v = lrelu(a1 * acc + d1);
      h1l[(bb * 64 + ch) * 10 + tt] = (tt >= 3) ? v : 0.f;
    }
  }
  __syncthreads();
  for (int e = tid; e < NB * NH2; e += 256) {
    int bb = e >> 7, o = e & 127;
    float a2 = coef2[o], d2 = coef2[NH2 + o], bo = b2c[o];
    float acc[4] = {bo, bo, bo, bo};
    for (int i = 0; i < 64; ++i)
      #pragma unroll
      for (int k = 0; k < 7; ++k) {
        float w = W2c[(o * 64 + i) * 7 + k];
        #pragma unroll
        for (int t = 0; t < 4; ++t)
          acc[t] += h1l[(bb * 64 + i) * 10 + t + k] * w;
      }
    #pragma unroll
    for (int t = 0; t < 4; ++t)
      h2l[(bb * NH2 + o) * 4 + t] = lrelu(a2 * acc[t] + d2);
  }
  __syncthreads();
  if (tid < 48) {
    int bb = tid / 6, c3 = tid % 6;
    float acc = b3c[c3];
    for (int c = 0; c < NH2; ++c)
      #pragma unroll
      for (int k = 3; k < 7; ++k)
        acc += h2l[(bb * NH2 + c) * 4 + (k - 3)] * W3c[(c3 * NH2 + c) * 7 + k];
    sp[tid] = tanhf(acc);
  }
  __syncthreads();
  if (tid < 16) {
    int bb = tid >> 1, i = tid & 1;
    float az = (sp[bb * 6 + i * 3 + 0] + 1.f) * 0.5f * 11.f;
    float el = (sp[bb * 6 + i * 3 + 1] + 1.f) * 0.5f * 4.f;
    float dist = (sp[bb * 6 + i * 3 + 2] + 1.f) * 0.5f * 0.9f + 0.1f;
    int azi = min(max((int)az, 0), 11);
    int eli = min(max((int)el, 0), 4);
    int idx = eli * 12 + azi;
    for (int e = 0; e < 14; ++e)
      wgbuf[(bb * 2 + i) * 14 + e] = hrtf[idx * 14 + e] * dist;
  }
}

// ---------------------------------------------------------------------------
// Kernel 6: summed[b,c,t] = sum_{i,k} x[b,i,t+k-3] * wg[b,i,c,k]
// ---------------------------------------------------------------------------
__global__ __launch_bounds__(256) void mix_kernel(
    const float* __restrict__ x, const float* __restrict__ wgbuf,
    float* __restrict__ summed)
{
  const int b = blockIdx.x >> 7;
  const int t0 = (blockIdx.x & 127) * 1024 + threadIdx.x * 4;
  float wv[2][2][7];
  #pragma unroll
  for (int i = 0; i < 2; ++i)
    #pragma unroll
    for (int c = 0; c < 2; ++c)
      #pragma unroll
      for (int k = 0; k < 7; ++k)
        wv[i][c][k] = wgbuf[(b * 2 + i) * 14 + c * 7 + k];
  float acc[2][4] = {{0.f, 0.f, 0.f, 0.f}, {0.f, 0.f, 0.f, 0.f}};
  #pragma unroll
  for (int i = 0; i < 2; ++i) {
    float xl[12];
    #pragma unroll
    for (int j = 0; j < 12; ++j) {
      int tg = t0 - 4 + j;
      xl[j] = (tg >= 0 && tg < TLEN) ? x[(b * 2 + i) * TLEN + tg] : 0.f;
    }
    #pragma unroll
    for (int c = 0; c < 2; ++c)
      #pragma unroll
      for (int k = 0; k < 7; ++k)
        #pragma unroll
        for (int tt = 0; tt < 4; ++tt)
          acc[c][tt] += xl[tt + k + 1] * wv[i][c][k];
  }
  #pragma unroll
  for (int c = 0; c < 2; ++c)
    *reinterpret_cast<float4*>(&summed[(b * 2 + c) * TLEN + t0]) =
        make_float4(acc[c][0], acc[c][1], acc[c][2], acc[c][3]);
}

// ---------------------------------------------------------------------------
// Kernel 11: 64-col tile. conv2 fp16 MFMA -> bn2+lrelu -> h2 fp16 [col][ch]
// (B-layout) -> conv3 fp16 MFMA (W3 as 16x896 A) -> tanh -> out.
// LDS 35,776 B (no aliasing of h2 region).
// ---------------------------------------------------------------------------
__global__ __launch_bounds__(256) void conv2_final_mfma(
    const float* __restrict__ xin,
    const float* __restrict__ W1c, const float* __restrict__ b1c,
    const float* __restrict__ coef1,
    const unsigned short* __restrict__ w2f,
    const float* __restrict__ b2c, const float* __restrict__ coef2,
    const unsigned short* __restrict__ w3f, const float* __restrict__ rb3c,
    float* __restrict__ out)
{
  const int b  = blockIdx.x >> 11;            // TLEN/64 = 2048 chunks
  const int t0 = (blockIdx.x & 2047) * 64;

  __shared__ __align__(16) char smem[35776];
  unsigned short* h1f = (unsigned short*)smem;      // [86][72], row r <-> t0-11+r
  float* xs  = (float*)(smem + 12384);              // [2][96], j <-> t0-14+j
  float* w1s = (float*)(smem + 13152);              // [64][14]
  unsigned short* h2t = (unsigned short*)(smem + 16736); // [70][136], row p <-> t0-3+p

  for (int e = threadIdx.x; e < 2 * 96; e += 256) {
    int i = e / 96, j = e % 96;
    int tg = t0 - 14 + j;
    xs[e] = (tg >= 0 && tg < TLEN) ? xin[(b * NICH + i) * TLEN + tg] : 0.f;
  }
  for (int e = threadIdx.x; e < 64 * 14; e += 256) w1s[e] = W1c[e];
  __syncthreads();

  for (int e = threadIdx.x; e < 86 * 16; e += 256) {
    int r = e >> 4, cg = e & 15;
    int t = t0 - 11 + r;
    bool ok = (t >= 0) && (t < TLEN);
    float a[2][7];
    #pragma unroll
    for (int i2 = 0; i2 < 2; ++i2)
      #pragma unroll
      for (int k = 0; k < 7; ++k) a[i2][k] = xs[i2 * 96 + r + k];
    unsigned u[4];
    #pragma unroll
    for (int cc = 0; cc < 4; ++cc) {
      int ch = cg * 4 + cc;
      float acc = b1c[ch];
      #pragma unroll
      for (int i2 = 0; i2 < 2; ++i2)
        #pragma unroll
        for (int k = 0; k < 7; ++k) acc += a[i2][k] * w1s[ch * 14 + i2 * 7 + k];
      float v = lrelu(coef1[ch] * acc + coef1[64 + ch]);
      u[cc] = h16(ok ? v : 0.f);
    }
    *(uint2*)(h1f + r * 72 + cg * 4) =
        make_uint2(u[0] | (u[1] << 16), u[2] | (u[3] << 16));
  }
  __syncthreads();

  const int lane = threadIdx.x & 63;
  const int wv = threadIdx.x >> 6;
  const int mn = lane & 15, quad = lane >> 4;
  const int o0w = wv * 32;

  f32x4 acc[2][5];
  #pragma unroll
  for (int mt = 0; mt < 2; ++mt)
    #pragma unroll
    for (int nt = 0; nt < 5; ++nt) {
      f32x4 z = {0.f, 0.f, 0.f, 0.f};
      acc[mt][nt] = z;
    }

  float b2v[2][4], a2v[2][4], d2v[2][4];
  #pragma unroll
  for (int mt = 0; mt < 2; ++mt)
    #pragma unroll
    for (int r = 0; r < 4; ++r) {
      int o = o0w + mt * 16 + quad * 4 + r;
      b2v[mt][r] = b2c[o];
      a2v[mt][r] = coef2[o];
      d2v[mt][r] = coef2[NH2 + o];
    }

  f16x8 ca[2], na[2];
  auto loadA = [&](int c, f16x8 (&A)[2]) {
    #pragma unroll
    for (int mt = 0; mt < 2; ++mt)
      A[mt] = *(const f16x8*)(w2f + (o0w + mt * 16 + mn) * 448 + c * 32 + quad * 8);
  };
  loadA(0, ca);
  for (int c = 0; c < 14; ++c) {
    if (c < 13) loadA(c + 1, na);
    const int tap = c >> 1;
    const int ch0 = (c & 1) * 32 + quad * 8;
    #pragma unroll
    for (int nt = 0; nt < 5; ++nt) {
      const int row = nt * 16 + mn + tap;
      f16x8 bb = *(const f16x8*)(h1f + row * 72 + ch0);
      acc[0][nt] = __builtin_amdgcn_mfma_f32_16x16x32_f16(ca[0], bb, acc[0][nt], 0, 0, 0);
      acc[1][nt] = __builtin_amdgcn_mfma_f32_16x16x32_f16(ca[1], bb, acc[1][nt], 0, 0, 0);
    }
    ca[0] = na[0]; ca[1] = na[1];
  }

  // bn2 + lrelu -> fp16 h2t [col][ch]; cols j in [5,75) -> rows p=j-5 (t0-3+p).
  // h2t is a disjoint LDS region: no barrier needed before writing.
  #pragma unroll
  for (int mt = 0; mt < 2; ++mt)
    #pragma unroll
    for (int nt = 0; nt < 5; ++nt) {
      int j = nt * 16 + mn;
      if (j >= 5 && j < 75) {
        int t = t0 - 8 + j;
        bool ok = (t >= 0) && (t < TLEN);
        unsigned u[4];
        #pragma unroll
        for (int r = 0; r < 4; ++r) {
          float v = acc[mt][nt][r] + b2v[mt][r];
          v = lrelu(a2v[mt][r] * v + d2v[mt][r]);
          u[r] = h16(ok ? v : 0.f);
        }
        int o0 = o0w + mt * 16 + quad * 4;
        *(uint2*)(h2t + (j - 5) * 136 + o0) =
            make_uint2(u[0] | (u[1] << 16), u[2] | (u[3] << 16));
      }
    }
  __syncthreads();

  // conv3 MFMA: D[m=outch(2 valid)][n=col16/wave], K=896 (tap*128+ch), 28 chunks.
  const int n0w = wv * 16;
  f32x4 acc3 = {0.f, 0.f, 0.f, 0.f};
  f16x8 a3c, a3n;
  a3c = *(const f16x8*)(w3f + mn * 896 + quad * 8);
  for (int c = 0; c < 28; ++c) {
    if (c < 27) a3n = *(const f16x8*)(w3f + mn * 896 + (c + 1) * 32 + quad * 8);
    const int tau = c >> 2;
    const int ch0 = (c & 3) * 32 + quad * 8;
    const int row = n0w + mn + tau;
    f16x8 bb = *(const f16x8*)(h2t + row * 136 + ch0);
    acc3 = __builtin_amdgcn_mfma_f32_16x16x32_f16(a3c, bb, acc3, 0, 0, 0);
    a3c = a3n;
  }
  if (quad == 0) {
    #pragma unroll
    for (int r = 0; r < 2; ++r)
      out[(b * 2 + r) * TLEN + t0 + n0w + mn] = tanhf(acc3[r] + rb3c[r]);
  }
}

// ---------------------------------------------------------------------------
extern "C" void kernel_launch(void* const* d_in, const int* in_sizes, int n_in,
                              void* d_out, int out_size, void* d_ws, size_t ws_size,
                              hipStream_t stream)
{
  (void)in_sizes; (void)n_in; (void)out_size; (void)ws_size;
  const float* x    = (const float*)d_in[0];
  const float* W1   = (const float*)d_in[1];
  const float* b1   = (const float*)d_in[2];
  const float* g1   = (const float*)d_in[3];
  const float* be1  = (const float*)d_in[4];
  const float* W2   = (const float*)d_in[5];
  const float* b2   = (const float*)d_in[6];
  const float* g2   = (const float*)d_in[7];
  const float* be2  = (const float*)d_in[8];
  const float* W3   = (const float*)d_in[9];
  const float* b3   = (const float*)d_in[10];
  const float* hrtf = (const float*)d_in[11];
  const float* RW1  = (const float*)d_in[12];
  const float* rb1  = (const float*)d_in[13];
  const float* rg1  = (const float*)d_in[14];
  const float* rbe1 = (const float*)d_in[15];
  const float* RW2  = (const float*)d_in[16];
  const float* rb2  = (const float*)d_in[17];
  const float* rg2  = (const float*)d_in[18];
  const float* rbe2 = (const float*)d_in[19];
  const float* RW3  = (const float*)d_in[20];
  const float* rb3  = (const float*)d_in[21];
  float* out = (float*)d_out;

  // d_out doubles as the 8192x256-f stats-partials buffer (lifetime ends
  // before conv2_final_mfma writes output).
  float* partialsB = (float*)d_out;

  char* ws = (char*)d_ws;
  float* partialsA      = (float*)(ws + 0);        // 524,288 B
  float* summed         = (float*)(ws + 524288);   // 8,388,608 B
  float* coef1          = (float*)(ws + 8912896);  // 128 f
  float* coef2          = (float*)(ws + 8913408);  // 256 f
  float* coefR1         = (float*)(ws + 8914432);  // 128 f
  float* coefR2         = (float*)(ws + 8914944);  // 256 f
  float* wgbuf          = (float*)(ws + 8915968);  // 224 f
  unsigned short* w2sp  = (unsigned short*)(ws + 8916992);  // 114,688 B
  unsigned short* w2re  = (unsigned short*)(ws + 9031680);  // 114,688 B
  unsigned short* w3f   = (unsigned short*)(ws + 9146368);  // 28,672 B
  // total ws use: 9,175,040 bytes

  prep_weights<<<504, 256, 0, stream>>>(W2, RW2, RW3, w2sp, w2re, w3f);
  // ---- spatial parameter network ----
  conv1_stats<<<1024, 256, 0, stream>>>(x, W1, b1, partialsA);
  reduce_coef<<<64, 256, 0, stream>>>(partialsA, 1024, 64, g1, be1, coef1);
  conv2_stats_mfma<<<8192, 256, 0, stream>>>(x, W1, b1, coef1, w2sp, b2, partialsB);
  reduce_coef<<<128, 256, 0, stream>>>(partialsB, 8192, 128, g2, be2, coef2);
  finalize_spatial<<<1, 256, 0, stream>>>(x, W1, b1, coef1, W2, b2, coef2,
                                          W3, b3, hrtf, wgbuf);
  // ---- HRTF mixing ----
  mix_kernel<<<1024, 256, 0, stream>>>(x, wgbuf, summed);
  // ---- binaural renderer ----
  conv1_stats<<<1024, 256, 0, stream>>>(summed, RW1, rb1, partialsA);
  reduce_coef<<<64, 256, 0, stream>>>(partialsA, 1024, 64, rg1, rbe1, coefR1);
  conv2_stats_mfma<<<8192, 256, 0, stream>>>(summed, RW1, rb1, coefR1,
                                             w2re, rb2, partialsB);
  reduce_coef<<<128, 256, 0, stream>>>(partialsB, 8192, 128, rg2, rbe2, coefR2);
  conv2_final_mfma<<<16384, 256, 0, stream>>>(summed, RW1, rb1, coefR1,
                                              w2re, rb2, coefR2, w3f, rb3, out);
}

// Round 6
// 1331.904 us; speedup vs baseline: 5.0068x; 1.0955x over previous
//
#include <hip/hip_runtime.h>
#include <hip/hip_fp16.h>
#include <cstddef>

// ---------------------------------------------------------------------------
// SpatialAudioRenderer on MI355X — v6: LDS-traffic-minimized MFMA pipeline.
//
// R5 counters: conv2_final 615us @ MfmaUtil 12 / VALU 21 -> LDS-pipe bound.
// v6: 128-col final tile; waves split N with all-M per wave (1 B-read -> 8
// MFMAs); vectorized h1 staging; conv3 as K=ch-only MFMA (tap-combine moved
// to a tiny D' gather). Output compared in bf16 (ulp 2^-8) -> fp16 links free.
// ---------------------------------------------------------------------------

#define TLEN 131072
#define NB 8
#define NICH 2
#define NHID 64
#define NH2 128
#define EPSV 1e-5f
#define CNTF 1048576.0f  // NB * TLEN

typedef _Float16 f16x8 __attribute__((ext_vector_type(8)));
typedef float f32x4 __attribute__((ext_vector_type(4)));

__device__ __forceinline__ float lrelu(float v) { return v >= 0.f ? v : 0.2f * v; }
__device__ __forceinline__ unsigned short h16(float v) {
  return __half_as_ushort(__float2half(v));
}
__device__ __forceinline__ float fh16(unsigned short u) {
  return __half2float(__ushort_as_half(u));
}

// ---------------------------------------------------------------------------
// Kernel 0: weight prep.
//  w2sp/w2re: [o][K=tap*64+ch] fp16, 128x448.
//  w3g:       [m=oc*7+tap][ch] fp16, 16x128 (rows 14,15 zero), from RW3.
// ---------------------------------------------------------------------------
__global__ __launch_bounds__(256) void prep_weights(
    const float* __restrict__ W2c, const float* __restrict__ RW2c,
    const float* __restrict__ RW3c,
    unsigned short* __restrict__ w2sp, unsigned short* __restrict__ w2re,
    unsigned short* __restrict__ w3g)
{
  int e = blockIdx.x * 256 + threadIdx.x;
  if (e < 57344) {
    int o = e / 448, K = e % 448;
    w2sp[e] = h16(W2c[(o * 64 + (K & 63)) * 7 + (K >> 6)]);
  } else if (e < 114688) {
    int e2 = e - 57344;
    int o = e2 / 448, K = e2 % 448;
    w2re[e2] = h16(RW2c[(o * 64 + (K & 63)) * 7 + (K >> 6)]);
  } else if (e < 116736) {
    int e2 = e - 114688;
    int m = e2 >> 7, ch = e2 & 127;
    w3g[e2] = (m < 14) ? h16(RW3c[((m / 7) * 128 + ch) * 7 + (m % 7)])
                       : (unsigned short)0;
  }
}

// ---------------------------------------------------------------------------
// Kernel 1/7: conv1 (Cin=2, Cout=64, K=7, SAME) -> per-block channel sum/sumsq.
// ---------------------------------------------------------------------------
#define TCH1 1024
__global__ __launch_bounds__(256) void conv1_stats(
    const float* __restrict__ x, const float* __restrict__ W,
    const float* __restrict__ bias, float* __restrict__ partials)
{
  const int b = blockIdx.x >> 7;
  const int t0 = (blockIdx.x & 127) * TCH1;
  __shared__ float xs[2 * 1032];
  __shared__ float red[512];

  for (int i = 0; i < 2; ++i)
    for (int j = threadIdx.x; j < TCH1 + 6; j += 256) {
      int tg = t0 - 3 + j;
      xs[i * 1032 + j] = (tg >= 0 && tg < TLEN) ? x[(b * NICH + i) * TLEN + tg] : 0.f;
    }
  __syncthreads();

  const int o = threadIdx.x & 63;
  const int sub = threadIdx.x >> 6;
  float w[14];
  #pragma unroll
  for (int j = 0; j < 14; ++j) w[j] = W[o * 14 + j];
  const float bo = bias[o];

  float s = 0.f, ss = 0.f;
  const int tbeg = sub * (TCH1 / 4), tend = tbeg + TCH1 / 4;
  for (int tt = tbeg; tt < tend; tt += 4) {
    float a4[2][10];
    #pragma unroll
    for (int i = 0; i < 2; ++i) {
      const float* xp = &xs[i * 1032 + tt];
      float4 v0 = *reinterpret_cast<const float4*>(xp);
      float4 v1 = *reinterpret_cast<const float4*>(xp + 4);
      float2 v2 = *reinterpret_cast<const float2*>(xp + 8);
      a4[i][0] = v0.x; a4[i][1] = v0.y; a4[i][2] = v0.z; a4[i][3] = v0.w;
      a4[i][4] = v1.x; a4[i][5] = v1.y; a4[i][6] = v1.z; a4[i][7] = v1.w;
      a4[i][8] = v2.x; a4[i][9] = v2.y;
    }
    #pragma unroll
    for (int tq = 0; tq < 4; ++tq) {
      float acc = bo;
      #pragma unroll
      for (int i = 0; i < 2; ++i)
        #pragma unroll
        for (int k = 0; k < 7; ++k)
          acc += a4[i][tq + k] * w[i * 7 + k];
      s += acc; ss += acc * acc;
    }
  }
  red[o * 4 + sub] = s;
  red[(64 + o) * 4 + sub] = ss;
  __syncthreads();
  if (threadIdx.x < 128) {
    const float* r = &red[threadIdx.x * 4];
    partials[blockIdx.x * 128 + threadIdx.x] = r[0] + r[1] + r[2] + r[3];
  }
}

// ---------------------------------------------------------------------------
// Kernel 2: reduce partials -> bn affine coefs.
// ---------------------------------------------------------------------------
__global__ __launch_bounds__(256) void reduce_coef(
    const float* __restrict__ partials, int nblocks, int C,
    const float* __restrict__ g, const float* __restrict__ be,
    float* __restrict__ coef)
{
  const int c = blockIdx.x;
  float s = 0.f, ss = 0.f;
  for (int j = threadIdx.x; j < nblocks; j += 256) {
    s  += partials[j * 2 * C + c];
    ss += partials[j * 2 * C + C + c];
  }
  #pragma unroll
  for (int off = 32; off >= 1; off >>= 1) {
    s  += __shfl_down(s, off, 64);
    ss += __shfl_down(ss, off, 64);
  }
  __shared__ float rs[4], rss[4];
  const int lane = threadIdx.x & 63, wv = threadIdx.x >> 6;
  if (lane == 0) { rs[wv] = s; rss[wv] = ss; }
  __syncthreads();
  if (threadIdx.x == 0) {
    float st  = rs[0] + rs[1] + rs[2] + rs[3];
    float sst = rss[0] + rss[1] + rss[2] + rss[3];
    float mean = st / CNTF;
    float var  = sst / CNTF - mean * mean;
    float a = g[c] * rsqrtf(var + EPSV);
    coef[c] = a;
    coef[C + c] = be[c] - mean * a;
  }
}

// ---------------------------------------------------------------------------
// Shared h1-compute helper (macro-ish via template): per-thread 4 ch x CPT
// cols, vectorized float4 xs reads (broadcast), W1T [k][ch] LDS layout.
// h1f row r <-> t = t0 - HOF + r.  xs col j <-> t = t0 - HOF - 3 + j; x
// needed for row r: j = r..r+6.
// ---------------------------------------------------------------------------
template<int CPT, int RMAX, int HOF>
__device__ __forceinline__ void h1_compute(
    int t0, const float* xs, const float* w1T,
    const float* __restrict__ coef1, const float* __restrict__ b1c,
    unsigned short* h1f)
{
  const int cgr = threadIdx.x & 15, cg2 = threadIdx.x >> 4;
  const int ch0 = cgr * 4;
  float wreg[4][14];
  #pragma unroll
  for (int q = 0; q < 14; ++q)
    #pragma unroll
    for (int cq = 0; cq < 4; ++cq)
      wreg[cq][q] = w1T[q * 64 + ch0 + cq];
  float a1v[4], d1v[4], b1v[4];
  #pragma unroll
  for (int cq = 0; cq < 4; ++cq) {
    a1v[cq] = coef1[ch0 + cq];
    d1v[cq] = coef1[64 + ch0 + cq];
    b1v[cq] = b1c[ch0 + cq];
  }
  const int r0 = cg2 * CPT;
  float xv[2][16];
  #pragma unroll
  for (int i2 = 0; i2 < 2; ++i2) {
    const float* xp = &xs[i2 * 168 + r0];
    float4 p0 = *reinterpret_cast<const float4*>(xp);
    float4 p1 = *reinterpret_cast<const float4*>(xp + 4);
    float4 p2 = *reinterpret_cast<const float4*>(xp + 8);
    float4 p3 = *reinterpret_cast<const float4*>(xp + 12);
    xv[i2][0] = p0.x;  xv[i2][1] = p0.y;  xv[i2][2] = p0.z;  xv[i2][3] = p0.w;
    xv[i2][4] = p1.x;  xv[i2][5] = p1.y;  xv[i2][6] = p1.z;  xv[i2][7] = p1.w;
    xv[i2][8] = p2.x;  xv[i2][9] = p2.y;  xv[i2][10] = p2.z; xv[i2][11] = p2.w;
    xv[i2][12] = p3.x; xv[i2][13] = p3.y; xv[i2][14] = p3.z; xv[i2][15] = p3.w;
  }
  #pragma unroll
  for (int cc = 0; cc < CPT; ++cc) {
    int r = r0 + cc;
    if (r < RMAX) {
      int t = t0 - HOF + r;
      bool ok = (t >= 0) && (t < TLEN);
      unsigned us[4];
      #pragma unroll
      for (int cq = 0; cq < 4; ++cq) {
        float acc = b1v[cq];
        #pragma unroll
        for (int i2 = 0; i2 < 2; ++i2)
          #pragma unroll
          for (int k = 0; k < 7; ++k)
            acc += xv[i2][cc + k] * wreg[cq][i2 * 7 + k];
        float v = lrelu(a1v[cq] * acc + d1v[cq]);
        us[cq] = h16(ok ? v : 0.f);
      }
      *(uint2*)(h1f + r * 72 + ch0) =
          make_uint2(us[0] | (us[1] << 16), us[2] | (us[3] << 16));
    }
  }
}

__device__ __forceinline__ void stage_x_w1(
    int t0, int xoff, const float* __restrict__ xin, int b,
    const float* __restrict__ W1c, float* xs, float* w1T)
{
  for (int e = threadIdx.x; e < 2 * 168; e += 256) {
    int i = e / 168, j = e % 168;
    int tg = t0 - xoff + j;
    xs[e] = (tg >= 0 && tg < TLEN) ? xin[(b * NICH + i) * TLEN + tg] : 0.f;
  }
  for (int e = threadIdx.x; e < 14 * 64; e += 256) {
    int q = e >> 6, ch = e & 63;
    w1T[e] = W1c[ch * 14 + q];
  }
}

// ---------------------------------------------------------------------------
// Kernel 3/9: conv2 via fp16 MFMA, stats only. 128 o x 128 t per block.
// 4 waves; wave w owns o [w*32, w*32+32) (2 M-tiles), all 8 N-tiles.
// ---------------------------------------------------------------------------
__global__ __launch_bounds__(256) void conv2_stats_mfma(
    const float* __restrict__ xin,
    const float* __restrict__ W1c, const float* __restrict__ b1c,
    const float* __restrict__ coef1,
    const unsigned short* __restrict__ w2f,
    const float* __restrict__ b2c,
    float* __restrict__ partials)
{
  const int b  = blockIdx.x >> 10;
  const int t0 = (blockIdx.x & 1023) * 128;

  __shared__ __align__(16) char smem[24224];
  unsigned short* h1f = (unsigned short*)smem;   // [134][72], r <-> t0-3+r
  float* xs   = (float*)(smem + 19296);          // [2][168], j <-> t0-6+j
  float* w1T  = (float*)(smem + 20640);          // [14][64]
  float* redS = (float*)smem;                    // [128][17] (aliases h1f, late)
  float* redSS= (float*)(smem + 8704);

  stage_x_w1(t0, 6, xin, b, W1c, xs, w1T);
  __syncthreads();
  h1_compute<9, 134, 3>(t0, xs, w1T, coef1, b1c, h1f);
  __syncthreads();

  const int lane = threadIdx.x & 63;
  const int wv = threadIdx.x >> 6;
  const int mn = lane & 15, quad = lane >> 4;
  const int o0w = wv * 32;

  f32x4 acc[2][8];
  #pragma unroll
  for (int mt = 0; mt < 2; ++mt)
    #pragma unroll
    for (int nt = 0; nt < 8; ++nt) {
      f32x4 z = {0.f, 0.f, 0.f, 0.f};
      acc[mt][nt] = z;
    }

  f16x8 ca[2], na[2];
  auto loadA = [&](int c, f16x8 (&A)[2]) {
    #pragma unroll
    for (int mt = 0; mt < 2; ++mt)
      A[mt] = *(const f16x8*)(w2f + (o0w + mt * 16 + mn) * 448 + c * 32 + quad * 8);
  };
  loadA(0, ca);
  #pragma unroll
  for (int c = 0; c < 14; ++c) {
    if (c < 13) loadA(c + 1, na);
    const int tap = c >> 1;
    const int ch0 = (c & 1) * 32 + quad * 8;
    #pragma unroll
    for (int nt = 0; nt < 8; ++nt) {
      const int row = nt * 16 + mn + tap;
      f16x8 bb = *(const f16x8*)(h1f + row * 72 + ch0);
      acc[0][nt] = __builtin_amdgcn_mfma_f32_16x16x32_f16(ca[0], bb, acc[0][nt], 0, 0, 0);
      acc[1][nt] = __builtin_amdgcn_mfma_f32_16x16x32_f16(ca[1], bb, acc[1][nt], 0, 0, 0);
    }
    ca[0] = na[0]; ca[1] = na[1];
  }
  __syncthreads();   // h1f dead; smem becomes reduction buffers

  #pragma unroll
  for (int mt = 0; mt < 2; ++mt)
    #pragma unroll
    for (int r = 0; r < 4; ++r) {
      int o = o0w + mt * 16 + quad * 4 + r;
      float bo = b2c[o];
      float s = 0.f, ss = 0.f;
      #pragma unroll
      for (int nt = 0; nt < 8; ++nt) {
        float v = acc[mt][nt][r] + bo;
        s += v; ss += v * v;
      }
      redS[o * 17 + mn] = s;
      redSS[o * 17 + mn] = ss;
    }
  __syncthreads();
  {
    int o = threadIdx.x & 127;
    const float* src = (threadIdx.x < 128) ? redS : redSS;
    float s = 0.f;
    #pragma unroll
    for (int j = 0; j < 16; ++j) s += src[o * 17 + j];
    partials[blockIdx.x * 256 + threadIdx.x] = s;
  }
}

// ---------------------------------------------------------------------------
// Kernel 5: fp32 recompute of c2 head + bn2 + conv3(t=0) + tanh -> HRTF gather.
// ---------------------------------------------------------------------------
__global__ __launch_bounds__(256) void finalize_spatial(
    const float* __restrict__ x,
    const float* __restrict__ W1c, const float* __restrict__ b1c,
    const float* __restrict__ coef1,
    const float* __restrict__ W2c, const float* __restrict__ b2c,
    const float* __restrict__ coef2,
    const float* __restrict__ W3c, const float* __restrict__ b3c,
    const float* __restrict__ hrtf, float* __restrict__ wgbuf)
{
  __shared__ float xl[NB * 2 * 16];
  __shared__ float h1l[NB * 64 * 10];
  __shared__ float h2l[NB * NH2 * 4];
  __shared__ float sp[48];
  const int tid = threadIdx.x;
  {
    int bb = tid >> 5, i = (tid >> 4) & 1, j = tid & 15;
    int t = j - 6;
    xl[tid] = (t >= 0) ? x[(bb * 2 + i) * TLEN + t] : 0.f;
  }
  __syncthreads();
  for (int e = tid; e < NB * 64; e += 256) {
    int bb = e >> 6, ch = e & 63;
    float a1 = coef1[ch], d1 = coef1[64 + ch], bo = b1c[ch];
    for (int tt = 0; tt < 10; ++tt) {
      float acc = bo;
      #pragma unroll
      for (int i2 = 0; i2 < 2; ++i2)
        #pragma unroll
        for (int k = 0; k < 7; ++k)
          acc += xl[(bb * 2 + i2) * 16 + tt + k] * W1c[ch * 14 + i2 * 7 + k];
      float v = lrelu(a1 * acc + d1);
      h1l[(bb * 64 + ch) * 10 + tt] = (tt >= 3) ? v : 0.f;
    }
  }
  __syncthreads();
  for (int e = tid; e < NB * NH2; e += 256) {
    int bb = e >> 7, o = e & 127;
    float a2 = coef2[o], d2 = coef2[NH2 + o], bo = b2c[o];
    float acc[4] = {bo, bo, bo, bo};
    for (int i = 0; i < 64; ++i)
      #pragma unroll
      for (int k = 0; k < 7; ++k) {
        float w = W2c[(o * 64 + i) * 7 + k];
        #pragma unroll
        for (int t = 0; t < 4; ++t)
          acc[t] += h1l[(bb * 64 + i) * 10 + t + k] * w;
      }
    #pragma unroll
    for (int t = 0; t < 4; ++t)
      h2l[(bb * NH2 + o) * 4 + t] = lrelu(a2 * acc[t] + d2);
  }
  __syncthreads();
  if (tid < 48) {
    int bb = tid / 6, c3 = tid % 6;
    float acc = b3c[c3];
    for (int c = 0; c < NH2; ++c)
      #pragma unroll
      for (int k = 3; k < 7; ++k)
        acc += h2l[(bb * NH2 + c) * 4 + (k - 3)] * W3c[(c3 * NH2 + c) * 7 + k];
    sp[tid] = tanhf(acc);
  }
  __syncthreads();
  if (tid < 16) {
    int bb = tid >> 1, i = tid & 1;
    float az = (sp[bb * 6 + i * 3 + 0] + 1.f) * 0.5f * 11.f;
    float el = (sp[bb * 6 + i * 3 + 1] + 1.f) * 0.5f * 4.f;
    float dist = (sp[bb * 6 + i * 3 + 2] + 1.f) * 0.5f * 0.9f + 0.1f;
    int azi = min(max((int)az, 0), 11);
    int eli = min(max((int)el, 0), 4);
    int idx = eli * 12 + azi;
    for (int e = 0; e < 14; ++e)
      wgbuf[(bb * 2 + i) * 14 + e] = hrtf[idx * 14 + e] * dist;
  }
}

// ---------------------------------------------------------------------------
// Kernel 6: summed[b,c,t] = sum_{i,k} x[b,i,t+k-3] * wg[b,i,c,k]
// ---------------------------------------------------------------------------
__global__ __launch_bounds__(256) void mix_kernel(
    const float* __restrict__ x, const float* __restrict__ wgbuf,
    float* __restrict__ summed)
{
  const int b = blockIdx.x >> 7;
  const int t0 = (blockIdx.x & 127) * 1024 + threadIdx.x * 4;
  float wv[2][2][7];
  #pragma unroll
  for (int i = 0; i < 2; ++i)
    #pragma unroll
    for (int c = 0; c < 2; ++c)
      #pragma unroll
      for (int k = 0; k < 7; ++k)
        wv[i][c][k] = wgbuf[(b * 2 + i) * 14 + c * 7 + k];
  float acc[2][4] = {{0.f, 0.f, 0.f, 0.f}, {0.f, 0.f, 0.f, 0.f}};
  #pragma unroll
  for (int i = 0; i < 2; ++i) {
    float xl[12];
    #pragma unroll
    for (int j = 0; j < 12; ++j) {
      int tg = t0 - 4 + j;
      xl[j] = (tg >= 0 && tg < TLEN) ? x[(b * 2 + i) * TLEN + tg] : 0.f;
    }
    #pragma unroll
    for (int c = 0; c < 2; ++c)
      #pragma unroll
      for (int k = 0; k < 7; ++k)
        #pragma unroll
        for (int tt = 0; tt < 4; ++tt)
          acc[c][tt] += xl[tt + k + 1] * wv[i][c][k];
  }
  #pragma unroll
  for (int c = 0; c < 2; ++c)
    *reinterpret_cast<float4*>(&summed[(b * 2 + c) * TLEN + t0]) =
        make_float4(acc[c][0], acc[c][1], acc[c][2], acc[c][3]);
}

// ---------------------------------------------------------------------------
// Kernel 11: 128-col tile.  h1 (fp16) -> conv2 MFMA (waves split N, all M per
// wave) -> bn2+lrelu -> h2t fp16 [col][ch] -> conv3 MFMA (A'=W3 16x128,
// K=ch only) -> D' fp16 [col][m] -> 7-tap gather + tanh -> out.
// LDS 60,768 B (xs/w1T alias h2t; D' aliases h1f).
// ---------------------------------------------------------------------------
__global__ __launch_bounds__(256) void conv2_final_mfma(
    const float* __restrict__ xin,
    const float* __restrict__ W1c, const float* __restrict__ b1c,
    const float* __restrict__ coef1,
    const unsigned short* __restrict__ w2f,
    const float* __restrict__ b2c, const float* __restrict__ coef2,
    const unsigned short* __restrict__ w3g, const float* __restrict__ rb3c,
    float* __restrict__ out)
{
  const int b  = blockIdx.x >> 10;            // TLEN/128 = 1024 chunks
  const int t0 = (blockIdx.x & 1023) * 128;

  __shared__ __align__(16) char smem[60768];
  unsigned short* h1f = (unsigned short*)smem;          // [150][72], r <-> t0-6+r
  unsigned short* h2t = (unsigned short*)(smem + 21600);// [144][136], j' <-> t0-3+j'
  float* xs  = (float*)(smem + 21600);                  // [2][168] (alias h2t, early)
  float* w1T = (float*)(smem + 22944);                  // [14][64]  (alias h2t, early)
  unsigned short* dq = (unsigned short*)smem;           // [144][22] (alias h1f, late)

  stage_x_w1(t0, 9, xin, b, W1c, xs, w1T);
  __syncthreads();
  h1_compute<10, 150, 6>(t0, xs, w1T, coef1, b1c, h1f);
  __syncthreads();     // xs/w1T dead after this point; h2t region free

  const int lane = threadIdx.x & 63;
  const int wv = threadIdx.x >> 6;
  const int mn = lane & 15, quad = lane >> 4;

  // ---- conv2: 14 K-chunks, 9 N-tiles (nt = wv + 4i), 8 M-tiles per wave ----
  f32x4 acc[8][3];
  #pragma unroll
  for (int mt = 0; mt < 8; ++mt)
    #pragma unroll
    for (int i = 0; i < 3; ++i) {
      f32x4 z = {0.f, 0.f, 0.f, 0.f};
      acc[mt][i] = z;
    }

  f16x8 Ac[8], An[8];
  #pragma unroll
  for (int mt = 0; mt < 8; ++mt)
    Ac[mt] = *(const f16x8*)(w2f + (mt * 16 + mn) * 448 + quad * 8);
  #pragma unroll
  for (int c = 0; c < 14; ++c) {
    if (c < 13)
      #pragma unroll
      for (int mt = 0; mt < 8; ++mt)
        An[mt] = *(const f16x8*)(w2f + (mt * 16 + mn) * 448 + (c + 1) * 32 + quad * 8);
    const int tap = c >> 1;
    const int ch0 = (c & 1) * 32 + quad * 8;
    #pragma unroll
    for (int i = 0; i < 3; ++i) {
      const int nt = wv + i * 4;
      if (nt < 9) {
        f16x8 bb = *(const f16x8*)(h1f + (nt * 16 + mn + tap) * 72 + ch0);
        #pragma unroll
        for (int mt = 0; mt < 8; ++mt)
          acc[mt][i] = __builtin_amdgcn_mfma_f32_16x16x32_f16(Ac[mt], bb, acc[mt][i], 0, 0, 0);
      }
    }
    #pragma unroll
    for (int mt = 0; mt < 8; ++mt) Ac[mt] = An[mt];
  }

  // ---- bn2 + lrelu -> h2t fp16 [j'][ch] ----
  #pragma unroll
  for (int i = 0; i < 3; ++i) {
    const int nt = wv + i * 4;
    if (nt < 9) {
      int jp = nt * 16 + mn;
      int t = t0 - 3 + jp;
      bool ok = (t >= 0) && (t < TLEN);
      #pragma unroll
      for (int mt = 0; mt < 8; ++mt) {
        unsigned us[4];
        #pragma unroll
        for (int r = 0; r < 4; ++r) {
          int o = mt * 16 + quad * 4 + r;
          float v = acc[mt][i][r] + b2c[o];
          v = lrelu(coef2[o] * v + coef2[NH2 + o]);
          us[r] = h16(ok ? v : 0.f);
        }
        *(uint2*)(h2t + jp * 136 + mt * 16 + quad * 4) =
            make_uint2(us[0] | (us[1] << 16), us[2] | (us[3] << 16));
      }
    }
  }
  __syncthreads();

  // ---- conv3: D'[m=oc*7+tap][n=j'] = sum_ch W3 * h2 (no tap in B) ----
  f32x4 acc3[3];
  #pragma unroll
  for (int i = 0; i < 3; ++i) {
    f32x4 z = {0.f, 0.f, 0.f, 0.f};
    acc3[i] = z;
  }
  f16x8 A3c = *(const f16x8*)(w3g + mn * 128 + quad * 8);
  f16x8 A3n;
  #pragma unroll
  for (int c = 0; c < 4; ++c) {
    if (c < 3) A3n = *(const f16x8*)(w3g + mn * 128 + (c + 1) * 32 + quad * 8);
    #pragma unroll
    for (int i = 0; i < 3; ++i) {
      const int nt = wv + i * 4;
      if (nt < 9) {
        f16x8 bb = *(const f16x8*)(h2t + (nt * 16 + mn) * 136 + c * 32 + quad * 8);
        acc3[i] = __builtin_amdgcn_mfma_f32_16x16x32_f16(A3c, bb, acc3[i], 0, 0, 0);
      }
    }
    A3c = A3n;
  }
  // store D' fp16 [n][m], stride 22 (8B-aligned uint2 at 44n+8q)
  #pragma unroll
  for (int i = 0; i < 3; ++i) {
    const int nt = wv + i * 4;
    if (nt < 9) {
      int n = nt * 16 + mn;
      unsigned us[4];
      #pragma unroll
      for (int r = 0; r < 4; ++r) us[r] = h16(acc3[i][r]);
      *(uint2*)(dq + n * 22 + quad * 4) =
          make_uint2(us[0] | (us[1] << 16), us[2] | (us[3] << 16));
    }
  }
  __syncthreads();

  // ---- gather: out[oc][u] = tanh(b3 + sum_tap D'[u+tap][oc*7+tap]) ----
  {
    int u = threadIdx.x & 127, oc = threadIdx.x >> 7;
    float s = rb3c[oc];
    #pragma unroll
    for (int tap = 0; tap < 7; ++tap)
      s += fh16(dq[(u + tap) * 22 + oc * 7 + tap]);
    out[(b * 2 + oc) * TLEN + t0 + u] = tanhf(s);
  }
}

// ---------------------------------------------------------------------------
extern "C" void kernel_launch(void* const* d_in, const int* in_sizes, int n_in,
                              void* d_out, int out_size, void* d_ws, size_t ws_size,
                              hipStream_t stream)
{
  (void)in_sizes; (void)n_in; (void)out_size; (void)ws_size;
  const float* x    = (const float*)d_in[0];
  const float* W1   = (const float*)d_in[1];
  const float* b1   = (const float*)d_in[2];
  const float* g1   = (const float*)d_in[3];
  const float* be1  = (const float*)d_in[4];
  const float* W2   = (const float*)d_in[5];
  const float* b2   = (const float*)d_in[6];
  const float* g2   = (const float*)d_in[7];
  const float* be2  = (const float*)d_in[8];
  const float* W3   = (const float*)d_in[9];
  const float* b3   = (const float*)d_in[10];
  const float* hrtf = (const float*)d_in[11];
  const float* RW1  = (const float*)d_in[12];
  const float* rb1  = (const float*)d_in[13];
  const float* rg1  = (const float*)d_in[14];
  const float* rbe1 = (const float*)d_in[15];
  const float* RW2  = (const float*)d_in[16];
  const float* rb2  = (const float*)d_in[17];
  const float* rg2  = (const float*)d_in[18];
  const float* rbe2 = (const float*)d_in[19];
  const float* RW3  = (const float*)d_in[20];
  const float* rb3  = (const float*)d_in[21];
  float* out = (float*)d_out;

  // d_out doubles as the 8192x256-f stats-partials buffer (lifetime ends
  // before conv2_final_mfma writes output).
  float* partialsB = (float*)d_out;

  char* ws = (char*)d_ws;
  float* partialsA      = (float*)(ws + 0);        // 524,288 B
  float* summed         = (float*)(ws + 524288);   // 8,388,608 B
  float* coef1          = (float*)(ws + 8912896);  // 128 f
  float* coef2          = (float*)(ws + 8913408);  // 256 f
  float* coefR1         = (float*)(ws + 8914432);  // 128 f
  float* coefR2         = (float*)(ws + 8914944);  // 256 f
  float* wgbuf          = (float*)(ws + 8915968);  // 224 f
  unsigned short* w2sp  = (unsigned short*)(ws + 8916992);  // 114,688 B
  unsigned short* w2re  = (unsigned short*)(ws + 9031680);  // 114,688 B
  unsigned short* w3g   = (unsigned short*)(ws + 9146368);  // 4,096 B
  // total ws use: 9,150,464 bytes

  prep_weights<<<456, 256, 0, stream>>>(W2, RW2, RW3, w2sp, w2re, w3g);
  // ---- spatial parameter network ----
  conv1_stats<<<1024, 256, 0, stream>>>(x, W1, b1, partialsA);
  reduce_coef<<<64, 256, 0, stream>>>(partialsA, 1024, 64, g1, be1, coef1);
  conv2_stats_mfma<<<8192, 256, 0, stream>>>(x, W1, b1, coef1, w2sp, b2, partialsB);
  reduce_coef<<<128, 256, 0, stream>>>(partialsB, 8192, 128, g2, be2, coef2);
  finalize_spatial<<<1, 256, 0, stream>>>(x, W1, b1, coef1, W2, b2, coef2,
                                          W3, b3, hrtf, wgbuf);
  // ---- HRTF mixing ----
  mix_kernel<<<1024, 256, 0, stream>>>(x, wgbuf, summed);
  // ---- binaural renderer ----
  conv1_stats<<<1024, 256, 0, stream>>>(summed, RW1, rb1, partialsA);
  reduce_coef<<<64, 256, 0, stream>>>(partialsA, 1024, 64, rg1, rbe1, coefR1);
  conv2_stats_mfma<<<8192, 256, 0, stream>>>(summed, RW1, rb1, coefR1,
                                             w2re, rb2, partialsB);
  reduce_coef<<<128, 256, 0, stream>>>(partialsB, 8192, 128, rg2, rbe2, coefR2);
  conv2_final_mfma<<<8192, 256, 0, stream>>>(summed, RW1, rb1, coefR1,
                                             w2re, rb2, coefR2, w3g, rb3, out);
}